// Round 2
// baseline (5047.799 us; speedup 1.0000x reference)
//
#include <hip/hip_runtime.h>
#include <math.h>

#define NN 20000
#define NE 200000
#define HIDC 96
#define NHEAD 6
#define HC 576   // NHEAD*HIDC

// ---------------------------------------------------------------------------
// Encoder: out = relu(LN(in @ W + b))   in: [rows, D], W: [D,96]
// one row per block, 128 threads
// ---------------------------------------------------------------------------
__global__ __launch_bounds__(128) void encode_kernel(
    const float* __restrict__ in, int D,
    const float* __restrict__ W, const float* __restrict__ b,
    const float* __restrict__ g, const float* __restrict__ beta,
    float* __restrict__ out) {
  int row = blockIdx.x;
  int t = threadIdx.x;
  __shared__ float vin[8];
  __shared__ float vals[96];
  __shared__ float red[2];
  if (t < D) vin[t] = in[row * D + t];
  __syncthreads();
  float v = 0.f;
  if (t < 96) {
    v = b[t];
    for (int k = 0; k < D; k++) v += vin[k] * W[k * 96 + t];
    vals[t] = v;
  }
  __syncthreads();
  if (t == 0) {
    float s = 0.f, s2 = 0.f;
    for (int k = 0; k < 96; k++) { float x = vals[k]; s += x; s2 += x * x; }
    float mu = s / 96.f;
    float var = s2 / 96.f - mu * mu;
    red[0] = mu; red[1] = rsqrtf(var + 1e-5f);
  }
  __syncthreads();
  if (t < 96) {
    float y = (v - red[0]) * red[1] * g[t] + beta[t];
    out[row * 96 + t] = fmaxf(y, 0.f);
  }
}

// ---------------------------------------------------------------------------
// CSR build by dst
// ---------------------------------------------------------------------------
__global__ void hist_kernel(const int* __restrict__ dst, int* __restrict__ deg) {
  int e = blockIdx.x * blockDim.x + threadIdx.x;
  if (e < NE) atomicAdd(&deg[dst[e]], 1);
}

__global__ __launch_bounds__(1024) void scan_kernel(
    const int* __restrict__ deg, int* __restrict__ rowptr, int* __restrict__ cursor) {
  __shared__ int buf[1024];
  __shared__ int carry_s;
  int t = threadIdx.x;
  if (t == 0) carry_s = 0;
  __syncthreads();
  for (int base = 0; base < NN; base += 1024) {
    int i = base + t;
    int v = (i < NN) ? deg[i] : 0;
    buf[t] = v;
    __syncthreads();
    for (int off = 1; off < 1024; off <<= 1) {
      int add = (t >= off) ? buf[t - off] : 0;
      __syncthreads();
      buf[t] += add;
      __syncthreads();
    }
    int carry = carry_s;
    int excl = carry + buf[t] - v;
    if (i < NN) { rowptr[i] = excl; cursor[i] = excl; }
    __syncthreads();
    if (t == 1023) carry_s = carry + buf[1023];
    __syncthreads();
  }
  if (t == 0) rowptr[NN] = NE;
}

__global__ void scatter_kernel(const int* __restrict__ dst,
                               int* __restrict__ cursor, int* __restrict__ eidx) {
  int e = blockIdx.x * blockDim.x + threadIdx.x;
  if (e < NE) {
    int p = atomicAdd(&cursor[dst[e]], 1);
    eidx[p] = e;
  }
}

// ---------------------------------------------------------------------------
// xl = x@Wl+bl, xr = x@Wr+br   (8 nodes per block, 576 threads = one col each)
// ---------------------------------------------------------------------------
__global__ __launch_bounds__(576) void xlxr_kernel(
    const float* __restrict__ x,
    const float* __restrict__ Wl, const float* __restrict__ bl,
    const float* __restrict__ Wr, const float* __restrict__ br,
    float* __restrict__ xl, float* __restrict__ xr) {
  __shared__ float xs[8][96];
  int t = threadIdx.x;
  int n0 = blockIdx.x * 8;
  for (int idx = t; idx < 8 * 96; idx += 576)
    xs[idx / 96][idx % 96] = x[(n0 + idx / 96) * 96 + idx % 96];
  __syncthreads();
  float aL[8], aR[8];
#pragma unroll
  for (int e = 0; e < 8; e++) { aL[e] = 0.f; aR[e] = 0.f; }
  for (int k = 0; k < 96; k += 4) {
    float wl0 = Wl[(k + 0) * 576 + t], wr0 = Wr[(k + 0) * 576 + t];
    float wl1 = Wl[(k + 1) * 576 + t], wr1 = Wr[(k + 1) * 576 + t];
    float wl2 = Wl[(k + 2) * 576 + t], wr2 = Wr[(k + 2) * 576 + t];
    float wl3 = Wl[(k + 3) * 576 + t], wr3 = Wr[(k + 3) * 576 + t];
#pragma unroll
    for (int e = 0; e < 8; e++) {
      float4 xv = *(const float4*)&xs[e][k];
      aL[e] += xv.x * wl0 + xv.y * wl1 + xv.z * wl2 + xv.w * wl3;
      aR[e] += xv.x * wr0 + xv.y * wr1 + xv.z * wr2 + xv.w * wr3;
    }
  }
  float bL = bl[t], bR = br[t];
#pragma unroll
  for (int e = 0; e < 8; e++) {
    xl[(n0 + e) * 576 + t] = aL[e] + bL;
    xr[(n0 + e) * 576 + t] = aR[e] + bR;
  }
}

// ---------------------------------------------------------------------------
// Fused: ee = emb@We ; h = leaky(xl[src]+xr[dst]+ee) ; logits = sum_c h*attw
// v2: 192 threads, 3 consecutive cols/thread, 16 edges/block.
// Each ds_read_b128 broadcast of emb feeds 12 FMA (3 cols x 4 k).
// Head = t/32 (3t..3t+2 never cross a 96-col head boundary); attw-dot reduced
// with shfl_xor over 32-lane groups -> no LDS round trip, no bank conflicts.
// ---------------------------------------------------------------------------
__global__ __launch_bounds__(192) void logits_kernel(
    const float* __restrict__ emb, const float* __restrict__ We,
    const float* __restrict__ attw, const float* __restrict__ xl,
    const float* __restrict__ xr, const int* __restrict__ src,
    const int* __restrict__ dst, float* __restrict__ logits) {
  __shared__ float es[16][96];
  __shared__ int sd[16][2];
  int t = threadIdx.x;
  int e0 = blockIdx.x * 16;
  // stage emb tile (16 rows x 96) as float4
  for (int idx = t; idx < 16 * 24; idx += 192) {
    int e = idx / 24, k4 = idx % 24;
    *(float4*)&es[e][k4 * 4] = *(const float4*)&emb[(size_t)(e0 + e) * 96 + k4 * 4];
  }
  if (t < 32) sd[t >> 1][t & 1] = (t & 1) ? dst[e0 + (t >> 1)] : src[e0 + (t >> 1)];
  __syncthreads();
  const int c0 = 3 * t;
  float acc0[16], acc1[16], acc2[16];
#pragma unroll
  for (int e = 0; e < 16; e++) { acc0[e] = 0.f; acc1[e] = 0.f; acc2[e] = 0.f; }
  for (int k = 0; k < 96; k += 4) {
    const float* Wk0 = We + (size_t)(k + 0) * 576 + c0;
    const float* Wk1 = We + (size_t)(k + 1) * 576 + c0;
    const float* Wk2 = We + (size_t)(k + 2) * 576 + c0;
    const float* Wk3 = We + (size_t)(k + 3) * 576 + c0;
    float wa0 = Wk0[0], wa1 = Wk1[0], wa2 = Wk2[0], wa3 = Wk3[0];
    float wb0 = Wk0[1], wb1 = Wk1[1], wb2 = Wk2[1], wb3 = Wk3[1];
    float wc0 = Wk0[2], wc1 = Wk1[2], wc2 = Wk2[2], wc3 = Wk3[2];
#pragma unroll
    for (int e = 0; e < 16; e++) {
      float4 ev = *(const float4*)&es[e][k];
      acc0[e] += ev.x * wa0 + ev.y * wa1 + ev.z * wa2 + ev.w * wa3;
      acc1[e] += ev.x * wb0 + ev.y * wb1 + ev.z * wb2 + ev.w * wb3;
      acc2[e] += ev.x * wc0 + ev.y * wc1 + ev.z * wc2 + ev.w * wc3;
    }
  }
  float aw0 = attw[c0], aw1 = attw[c0 + 1], aw2 = attw[c0 + 2];
  int h = t >> 5;  // head = (3t)/96 = t/32
#pragma unroll
  for (int e = 0; e < 16; e++) {
    const float* xls = &xl[(size_t)sd[e][0] * 576 + c0];
    const float* xrs = &xr[(size_t)sd[e][1] * 576 + c0];
    float v0 = acc0[e] + xls[0] + xrs[0];
    float v1 = acc1[e] + xls[1] + xrs[1];
    float v2 = acc2[e] + xls[2] + xrs[2];
    v0 = (v0 > 0.f) ? v0 : 0.2f * v0;
    v1 = (v1 > 0.f) ? v1 : 0.2f * v1;
    v2 = (v2 > 0.f) ? v2 : 0.2f * v2;
    float p = v0 * aw0 + v1 * aw1 + v2 * aw2;
    p += __shfl_xor(p, 16);
    p += __shfl_xor(p, 8);
    p += __shfl_xor(p, 4);
    p += __shfl_xor(p, 2);
    p += __shfl_xor(p, 1);
    if ((t & 31) == 0) logits[(size_t)(e0 + e) * 6 + h] = p;
  }
}

// ---------------------------------------------------------------------------
// Per-dst-node: segment softmax + weighted sum of xl[src] + head mean + cbias
// + (elu) + LN + residual, in-place update of x. one node per block, 576 thr.
// ---------------------------------------------------------------------------
__global__ __launch_bounds__(576) void aggregate_kernel(
    float* __restrict__ x, const float* __restrict__ xl,
    const float* __restrict__ logits, const int* __restrict__ rowptr,
    const int* __restrict__ eidx, const int* __restrict__ src,
    const float* __restrict__ cbias, const float* __restrict__ lng,
    const float* __restrict__ lnb, int do_elu) {
  int n = blockIdx.x;
  int t = threadIdx.x;
  int r0 = rowptr[n], r1 = rowptr[n + 1];
  int d = r1 - r0;
  __shared__ float mh[6], dh[6];
  __shared__ float scratch[576];
  __shared__ float fin[96];
  __shared__ float red[2];
  int h6 = t % 6;  // 576 % 6 == 0 -> each thread always same head in A/B
  // phase A: per-head max
  float lmax = -1e30f;
  for (int i = t; i < d * 6; i += 576) {
    int e = eidx[r0 + i / 6];
    lmax = fmaxf(lmax, logits[e * 6 + h6]);
  }
  scratch[t] = lmax;
  __syncthreads();
  if (t < 6) {
    float m = -1e30f;
    for (int g2 = t; g2 < 576; g2 += 6) m = fmaxf(m, scratch[g2]);
    mh[t] = m;
  }
  __syncthreads();
  // phase B: per-head sum of exp
  float lsum = 0.f;
  float mloc = mh[h6];
  for (int i = t; i < d * 6; i += 576) {
    int e = eidx[r0 + i / 6];
    lsum += expf(logits[e * 6 + h6] - mloc);
  }
  __syncthreads();
  scratch[t] = lsum;
  __syncthreads();
  if (t < 6) {
    float s = 0.f;
    for (int g2 = t; g2 < 576; g2 += 6) s += scratch[g2];
    dh[t] = s;
  }
  __syncthreads();
  // phase C: weighted accumulate
  int h = t / 96;
  float mhv = mh[h];
  float rdh = 1.f / (dh[h] + 1e-16f);
  float acc = 0.f;
  for (int i = 0; i < d; i++) {
    int e = eidx[r0 + i];
    float a = expf(logits[e * 6 + h] - mhv) * rdh;
    acc += a * xl[(size_t)src[e] * 576 + t];
  }
  __syncthreads();
  scratch[t] = acc;
  __syncthreads();
  // head mean + cbias + elu
  if (t < 96) {
    float s = 0.f;
    for (int hh = 0; hh < 6; hh++) s += scratch[hh * 96 + t];
    s = s * (1.f / 6.f) + cbias[t];
    if (do_elu) s = (s > 0.f) ? s : expm1f(s);
    fin[t] = s;
  }
  __syncthreads();
  if (t == 0) {
    float s = 0.f, s2 = 0.f;
    for (int k = 0; k < 96; k++) { float v = fin[k]; s += v; s2 += v * v; }
    float mu = s / 96.f;
    float var = s2 / 96.f - mu * mu;
    red[0] = mu; red[1] = rsqrtf(var + 1e-5f);
  }
  __syncthreads();
  if (t < 96) {
    float y = (fin[t] - red[0]) * red[1] * lng[t] + lnb[t];
    x[n * 96 + t] = x[n * 96 + t] + y;
  }
}

// ---------------------------------------------------------------------------
// Predictor: per edge  ctx=[x[src],x[dst],emb] -> LN(relu)->.. -> scalar
// 16 edges per block, 128 threads
// ---------------------------------------------------------------------------
__global__ __launch_bounds__(128) void pred_kernel(
    const float* __restrict__ x, const float* __restrict__ emb,
    const int* __restrict__ src, const int* __restrict__ dst,
    const float* __restrict__ p1w, const float* __restrict__ p1b,
    const float* __restrict__ p1g, const float* __restrict__ p1be,
    const float* __restrict__ p2w, const float* __restrict__ p2b,
    const float* __restrict__ p2g, const float* __restrict__ p2be,
    const float* __restrict__ p3w, const float* __restrict__ p3b,
    float* __restrict__ out) {
  __shared__ float ctx[16][288];
  __shared__ float h1[16][128];
  __shared__ float h2[16][64];
  __shared__ float musig[16][2];
  int t = threadIdx.x;
  int e0 = blockIdx.x * 16;
  for (int idx = t; idx < 16 * 288; idx += 128) {
    int e = idx / 288, j = idx % 288;
    float v;
    if (j < 96) v = x[src[e0 + e] * 96 + j];
    else if (j < 192) v = x[dst[e0 + e] * 96 + (j - 96)];
    else v = emb[(e0 + e) * 96 + (j - 192)];
    ctx[e][j] = v;
  }
  __syncthreads();
  float a1[16];
#pragma unroll
  for (int e = 0; e < 16; e++) a1[e] = 0.f;
  for (int k = 0; k < 288; k += 4) {
    float w0 = p1w[(k + 0) * 128 + t];
    float w1 = p1w[(k + 1) * 128 + t];
    float w2 = p1w[(k + 2) * 128 + t];
    float w3 = p1w[(k + 3) * 128 + t];
#pragma unroll
    for (int e = 0; e < 16; e++) {
      float4 cv = *(const float4*)&ctx[e][k];
      a1[e] += cv.x * w0 + cv.y * w1 + cv.z * w2 + cv.w * w3;
    }
  }
  float b1 = p1b[t];
#pragma unroll
  for (int e = 0; e < 16; e++) h1[e][t] = a1[e] + b1;
  __syncthreads();
  if (t < 16) {
    float s = 0.f, s2 = 0.f;
    for (int k = 0; k < 128; k++) { float v = h1[t][k]; s += v; s2 += v * v; }
    float mu = s / 128.f;
    float var = s2 / 128.f - mu * mu;
    musig[t][0] = mu; musig[t][1] = rsqrtf(var + 1e-5f);
  }
  __syncthreads();
  float g1 = p1g[t], be1 = p1be[t];
#pragma unroll
  for (int e = 0; e < 16; e++) {
    float v = (h1[e][t] - musig[e][0]) * musig[e][1] * g1 + be1;
    h1[e][t] = fmaxf(v, 0.f);
  }
  __syncthreads();
  if (t < 64) {
    float a2[16];
#pragma unroll
    for (int e = 0; e < 16; e++) a2[e] = 0.f;
    for (int k = 0; k < 128; k++) {
      float w = p2w[k * 64 + t];
#pragma unroll
      for (int e = 0; e < 16; e++) a2[e] += h1[e][k] * w;
    }
    float b2 = p2b[t];
#pragma unroll
    for (int e = 0; e < 16; e++) h2[e][t] = a2[e] + b2;
  }
  __syncthreads();
  if (t < 16) {
    float s = 0.f, s2 = 0.f;
    for (int k = 0; k < 64; k++) { float v = h2[t][k]; s += v; s2 += v * v; }
    float mu = s / 64.f;
    float var = s2 / 64.f - mu * mu;
    musig[t][0] = mu; musig[t][1] = rsqrtf(var + 1e-5f);
  }
  __syncthreads();
  if (t < 64) {
    float g2v = p2g[t], be2 = p2be[t];
#pragma unroll
    for (int e = 0; e < 16; e++) {
      float v = (h2[e][t] - musig[e][0]) * musig[e][1] * g2v + be2;
      h2[e][t] = fmaxf(v, 0.f);
    }
  }
  __syncthreads();
  if (t < 16) {
    float s = p3b[0];
    for (int k = 0; k < 64; k++) s += h2[t][k] * p3w[k];
    out[e0 + t] = s;
  }
}

// ---------------------------------------------------------------------------
extern "C" void kernel_launch(void* const* d_in, const int* in_sizes, int n_in,
                              void* d_out, int out_size, void* d_ws, size_t ws_size,
                              hipStream_t stream) {
  const float* x_in      = (const float*)d_in[0];
  const float* edge_attr = (const float*)d_in[1];
  const int*   ei        = (const int*)d_in[2];
  const int* src = ei;
  const int* dst = ei + NE;
  const float* ne_w = (const float*)d_in[3];
  const float* ne_b = (const float*)d_in[4];
  const float* ne_g = (const float*)d_in[5];
  const float* ne_be = (const float*)d_in[6];
  const float* ee_w = (const float*)d_in[7];
  const float* ee_b = (const float*)d_in[8];
  const float* ee_g = (const float*)d_in[9];
  const float* ee_be = (const float*)d_in[10];
  const float* Wl = (const float*)d_in[11];
  const float* bl = (const float*)d_in[12];
  const float* Wr = (const float*)d_in[13];
  const float* br = (const float*)d_in[14];
  const float* We = (const float*)d_in[15];
  const float* attw = (const float*)d_in[16];
  const float* cbias = (const float*)d_in[17];
  const float* lng = (const float*)d_in[18];
  const float* lnb = (const float*)d_in[19];
  const float* p1w = (const float*)d_in[20];
  const float* p1b = (const float*)d_in[21];
  const float* p1g = (const float*)d_in[22];
  const float* p1be = (const float*)d_in[23];
  const float* p2w = (const float*)d_in[24];
  const float* p2b = (const float*)d_in[25];
  const float* p2g = (const float*)d_in[26];
  const float* p2be = (const float*)d_in[27];
  const float* p3w = (const float*)d_in[28];
  const float* p3b = (const float*)d_in[29];
  float* out = (float*)d_out;

  // workspace carve
  char* w = (char*)d_ws;
  float* X   = (float*)w; w += (size_t)NN * 96 * 4;
  float* EMB = (float*)w; w += (size_t)NE * 96 * 4;
  float* XL  = (float*)w; w += (size_t)NN * 576 * 4;
  float* XR  = (float*)w; w += (size_t)NN * 576 * 4;
  float* LOG = (float*)w; w += (size_t)NE * 6 * 4;
  int* deg    = (int*)w; w += (size_t)(NN + 1) * 4;
  int* rowptr = (int*)w; w += (size_t)(NN + 1) * 4;
  int* cursor = (int*)w; w += (size_t)NN * 4;
  int* eidx   = (int*)w; w += (size_t)NE * 4;

  // encoders
  encode_kernel<<<NN, 128, 0, stream>>>(x_in, 4, ne_w, ne_b, ne_g, ne_be, X);
  encode_kernel<<<NE, 128, 0, stream>>>(edge_attr, 3, ee_w, ee_b, ee_g, ee_be, EMB);

  // CSR by dst
  hipMemsetAsync(deg, 0, (size_t)(NN + 1) * 4, stream);
  hist_kernel<<<(NE + 255) / 256, 256, 0, stream>>>(dst, deg);
  scan_kernel<<<1, 1024, 0, stream>>>(deg, rowptr, cursor);
  scatter_kernel<<<(NE + 255) / 256, 256, 0, stream>>>(dst, cursor, eidx);

  // 3 GATv2 layers
  for (int i = 0; i < 3; i++) {
    const float* Wl_i = Wl + (size_t)i * 96 * 576;
    const float* bl_i = bl + (size_t)i * 576;
    const float* Wr_i = Wr + (size_t)i * 96 * 576;
    const float* br_i = br + (size_t)i * 576;
    const float* We_i = We + (size_t)i * 96 * 576;
    const float* aw_i = attw + (size_t)i * 576;
    const float* cb_i = cbias + (size_t)i * 96;
    const float* lg_i = lng + (size_t)i * 96;
    const float* lb_i = lnb + (size_t)i * 96;
    xlxr_kernel<<<NN / 8, 576, 0, stream>>>(X, Wl_i, bl_i, Wr_i, br_i, XL, XR);
    logits_kernel<<<NE / 16, 192, 0, stream>>>(EMB, We_i, aw_i, XL, XR, src, dst, LOG);
    aggregate_kernel<<<NN, 576, 0, stream>>>(X, XL, LOG, rowptr, eidx, src,
                                             cb_i, lg_i, lb_i, (i < 2) ? 1 : 0);
  }

  // predictor
  pred_kernel<<<NE / 16, 128, 0, stream>>>(X, EMB, src, dst,
                                           p1w, p1b, p1g, p1be,
                                           p2w, p2b, p2g, p2be,
                                           p3w, p3b, out);
}

// Round 3
// 3194.452 us; speedup vs baseline: 1.5802x; 1.5802x over previous
//
#include <hip/hip_runtime.h>
#include <math.h>

#define NN 20000
#define NE 200000
#define HIDC 96
#define NHEAD 6
#define HC 576   // NHEAD*HIDC

typedef __attribute__((ext_vector_type(8))) short bf16x8;
typedef __attribute__((ext_vector_type(4))) float f32x4;

__device__ __forceinline__ unsigned short f2bf(float x) {
  union { float f; unsigned u; } c; c.f = x;
  unsigned r = c.u + 0x7FFF + ((c.u >> 16) & 1);
  return (unsigned short)(r >> 16);
}
__device__ __forceinline__ float bf2f(unsigned short u) {
  union { unsigned u; float f; } c; c.u = ((unsigned)u) << 16;
  return c.f;
}

// ---------------------------------------------------------------------------
// Encoder: out = relu(LN(in @ W + b))   in: [rows, D], W: [D,96]
// one row per block, 128 threads. Optionally writes a bf16 copy.
// ---------------------------------------------------------------------------
__global__ __launch_bounds__(128) void encode_kernel(
    const float* __restrict__ in, int D,
    const float* __restrict__ W, const float* __restrict__ b,
    const float* __restrict__ g, const float* __restrict__ beta,
    float* __restrict__ out, unsigned short* __restrict__ outb) {
  int row = blockIdx.x;
  int t = threadIdx.x;
  __shared__ float vin[8];
  __shared__ float vals[96];
  __shared__ float red[2];
  if (t < D) vin[t] = in[row * D + t];
  __syncthreads();
  float v = 0.f;
  if (t < 96) {
    v = b[t];
    for (int k = 0; k < D; k++) v += vin[k] * W[k * 96 + t];
    vals[t] = v;
  }
  __syncthreads();
  if (t == 0) {
    float s = 0.f, s2 = 0.f;
    for (int k = 0; k < 96; k++) { float x = vals[k]; s += x; s2 += x * x; }
    float mu = s / 96.f;
    float var = s2 / 96.f - mu * mu;
    red[0] = mu; red[1] = rsqrtf(var + 1e-5f);
  }
  __syncthreads();
  if (t < 96) {
    float y = (v - red[0]) * red[1] * g[t] + beta[t];
    y = fmaxf(y, 0.f);
    out[(size_t)row * 96 + t] = y;
    if (outb) outb[(size_t)row * 96 + t] = f2bf(y);
  }
}

// ---------------------------------------------------------------------------
// We [3][96][576] fp32 -> WeTb [3][576][96] bf16 (transposed per layer)
// ---------------------------------------------------------------------------
__global__ void convWeT_kernel(const float* __restrict__ We,
                               unsigned short* __restrict__ WeTb) {
  int idx = blockIdx.x * 256 + threadIdx.x;
  if (idx < 3 * 576 * 96) {
    int l = idx / (576 * 96);
    int rem = idx % (576 * 96);
    int n = rem / 96, k = rem % 96;
    WeTb[idx] = f2bf(We[(size_t)l * 96 * 576 + (size_t)k * 576 + n]);
  }
}

// ---------------------------------------------------------------------------
// CSR build by dst
// ---------------------------------------------------------------------------
__global__ void hist_kernel(const int* __restrict__ dst, int* __restrict__ deg) {
  int e = blockIdx.x * blockDim.x + threadIdx.x;
  if (e < NE) atomicAdd(&deg[dst[e]], 1);
}

__global__ __launch_bounds__(1024) void scan_kernel(
    const int* __restrict__ deg, int* __restrict__ rowptr, int* __restrict__ cursor) {
  __shared__ int buf[1024];
  __shared__ int carry_s;
  int t = threadIdx.x;
  if (t == 0) carry_s = 0;
  __syncthreads();
  for (int base = 0; base < NN; base += 1024) {
    int i = base + t;
    int v = (i < NN) ? deg[i] : 0;
    buf[t] = v;
    __syncthreads();
    for (int off = 1; off < 1024; off <<= 1) {
      int add = (t >= off) ? buf[t - off] : 0;
      __syncthreads();
      buf[t] += add;
      __syncthreads();
    }
    int carry = carry_s;
    int excl = carry + buf[t] - v;
    if (i < NN) { rowptr[i] = excl; cursor[i] = excl; }
    __syncthreads();
    if (t == 1023) carry_s = carry + buf[1023];
    __syncthreads();
  }
  if (t == 0) rowptr[NN] = NE;
}

__global__ void scatter_kernel(const int* __restrict__ dst,
                               int* __restrict__ cursor, int* __restrict__ eidx) {
  int e = blockIdx.x * blockDim.x + threadIdx.x;
  if (e < NE) {
    int p = atomicAdd(&cursor[dst[e]], 1);
    eidx[p] = e;
  }
}

// ---------------------------------------------------------------------------
// xl = x@Wl+bl (fp32 + bf16 copies), xr = x@Wr+br (bf16 only)
// 8 nodes per block, 576 threads = one col each
// ---------------------------------------------------------------------------
__global__ __launch_bounds__(576) void xlxr_kernel(
    const float* __restrict__ x,
    const float* __restrict__ Wl, const float* __restrict__ bl,
    const float* __restrict__ Wr, const float* __restrict__ br,
    float* __restrict__ xl, unsigned short* __restrict__ xlb,
    unsigned short* __restrict__ xrb) {
  __shared__ float xs[8][96];
  int t = threadIdx.x;
  int n0 = blockIdx.x * 8;
  for (int idx = t; idx < 8 * 96; idx += 576)
    xs[idx / 96][idx % 96] = x[(size_t)(n0 + idx / 96) * 96 + idx % 96];
  __syncthreads();
  float aL[8], aR[8];
#pragma unroll
  for (int e = 0; e < 8; e++) { aL[e] = 0.f; aR[e] = 0.f; }
  for (int k = 0; k < 96; k += 4) {
    float wl0 = Wl[(k + 0) * 576 + t], wr0 = Wr[(k + 0) * 576 + t];
    float wl1 = Wl[(k + 1) * 576 + t], wr1 = Wr[(k + 1) * 576 + t];
    float wl2 = Wl[(k + 2) * 576 + t], wr2 = Wr[(k + 2) * 576 + t];
    float wl3 = Wl[(k + 3) * 576 + t], wr3 = Wr[(k + 3) * 576 + t];
#pragma unroll
    for (int e = 0; e < 8; e++) {
      float4 xv = *(const float4*)&xs[e][k];
      aL[e] += xv.x * wl0 + xv.y * wl1 + xv.z * wl2 + xv.w * wl3;
      aR[e] += xv.x * wr0 + xv.y * wr1 + xv.z * wr2 + xv.w * wr3;
    }
  }
  float bL = bl[t], bR = br[t];
#pragma unroll
  for (int e = 0; e < 8; e++) {
    float vl = aL[e] + bL;
    float vr = aR[e] + bR;
    xl[(size_t)(n0 + e) * 576 + t] = vl;
    xlb[(size_t)(n0 + e) * 576 + t] = f2bf(vl);
    xrb[(size_t)(n0 + e) * 576 + t] = f2bf(vr);
  }
}

// ---------------------------------------------------------------------------
// Fused logits via MFMA bf16: ee = emb@We ; h = leaky(xl[src]+xr[dst]+ee);
// logits[e][h] = sum_c h*attw.
// Block = 256 thr (4 waves), 64 edges/block, wave w handles edges 16w..16w+15.
// A (emb rows) in registers, reused over 36 N-tiles; B from WeTb (bf16,
// transposed [576][96]) via L1/L2; xl/xr gathered as bf16 per tile.
// ---------------------------------------------------------------------------
__global__ __launch_bounds__(256) void logits_mfma_kernel(
    const unsigned short* __restrict__ EMBb,   // [NE][96]
    const unsigned short* __restrict__ WeTb,   // [576][96]
    const float* __restrict__ attw,            // [576]
    const unsigned short* __restrict__ XLb,    // [NN][576]
    const unsigned short* __restrict__ XRb,    // [NN][576]
    const int* __restrict__ src, const int* __restrict__ dst,
    float* __restrict__ logits) {
  __shared__ int sd[64][2];
  int t = threadIdx.x;
  int e0 = blockIdx.x * 64;
  if (t < 128) {
    int e = t >> 1;
    sd[e][t & 1] = (t & 1) ? dst[e0 + e] : src[e0 + e];
  }
  __syncthreads();
  int wave = t >> 6;
  int lane = t & 63;
  int l15 = lane & 15;
  int quad = lane >> 4;
  // A fragments: lane holds emb row (e0+16w+l15), k = 32*ka + 8*quad + j
  const unsigned short* arow = &EMBb[(size_t)(e0 + wave * 16 + l15) * 96 + quad * 8];
  bf16x8 a0 = *(const bf16x8*)&arow[0];
  bf16x8 a1 = *(const bf16x8*)&arow[32];
  bf16x8 a2 = *(const bf16x8*)&arow[64];
  float part[4][6];
#pragma unroll
  for (int r = 0; r < 4; r++)
#pragma unroll
    for (int h = 0; h < 6; h++) part[r][h] = 0.f;

  for (int tt = 0; tt < 36; tt++) {
    int n0 = tt * 16;
    int col = n0 + l15;
    // B fragments: lane holds WeT row (n0+l15) = We column, same k chunks
    const unsigned short* brow = &WeTb[(size_t)col * 96 + quad * 8];
    bf16x8 b0 = *(const bf16x8*)&brow[0];
    bf16x8 b1 = *(const bf16x8*)&brow[32];
    bf16x8 b2 = *(const bf16x8*)&brow[64];
    f32x4 acc = {0.f, 0.f, 0.f, 0.f};
    acc = __builtin_amdgcn_mfma_f32_16x16x32_bf16(a0, b0, acc, 0, 0, 0);
    acc = __builtin_amdgcn_mfma_f32_16x16x32_bf16(a1, b1, acc, 0, 0, 0);
    acc = __builtin_amdgcn_mfma_f32_16x16x32_bf16(a2, b2, acc, 0, 0, 0);
    float aw = attw[col];
    int hh = tt / 6;
#pragma unroll
    for (int r = 0; r < 4; r++) {
      int el = wave * 16 + quad * 4 + r;   // C row = quad*4+r
      float xlv = bf2f(XLb[(size_t)sd[el][0] * 576 + col]);
      float xrv = bf2f(XRb[(size_t)sd[el][1] * 576 + col]);
      float v = acc[r] + xlv + xrv;
      v = (v > 0.f) ? v : 0.2f * v;
      part[r][hh] += v * aw;
    }
  }
  // reduce over the 16 cols held by lanes l15=0..15 (within each quad)
#pragma unroll
  for (int r = 0; r < 4; r++)
#pragma unroll
    for (int h = 0; h < 6; h++) {
      float p = part[r][h];
      p += __shfl_xor(p, 1);
      p += __shfl_xor(p, 2);
      p += __shfl_xor(p, 4);
      p += __shfl_xor(p, 8);
      part[r][h] = p;
    }
  if (l15 == 0) {
    int el = e0 + wave * 16 + quad * 4;
#pragma unroll
    for (int r = 0; r < 4; r++)
#pragma unroll
      for (int h = 0; h < 6; h++)
        logits[(size_t)(el + r) * 6 + h] = part[r][h];
  }
}

// ---------------------------------------------------------------------------
// Per-dst-node: segment softmax + weighted sum of xl[src] + head mean + cbias
// + (elu) + LN + residual, in-place update of x. one node per block, 576 thr.
// ---------------------------------------------------------------------------
__global__ __launch_bounds__(576) void aggregate_kernel(
    float* __restrict__ x, const float* __restrict__ xl,
    const float* __restrict__ logits, const int* __restrict__ rowptr,
    const int* __restrict__ eidx, const int* __restrict__ src,
    const float* __restrict__ cbias, const float* __restrict__ lng,
    const float* __restrict__ lnb, int do_elu) {
  int n = blockIdx.x;
  int t = threadIdx.x;
  int r0 = rowptr[n], r1 = rowptr[n + 1];
  int d = r1 - r0;
  __shared__ float mh[6], dh[6];
  __shared__ float scratch[576];
  __shared__ float fin[96];
  __shared__ float red[2];
  int h6 = t % 6;
  float lmax = -1e30f;
  for (int i = t; i < d * 6; i += 576) {
    int e = eidx[r0 + i / 6];
    lmax = fmaxf(lmax, logits[(size_t)e * 6 + h6]);
  }
  scratch[t] = lmax;
  __syncthreads();
  if (t < 6) {
    float m = -1e30f;
    for (int g2 = t; g2 < 576; g2 += 6) m = fmaxf(m, scratch[g2]);
    mh[t] = m;
  }
  __syncthreads();
  float lsum = 0.f;
  float mloc = mh[h6];
  for (int i = t; i < d * 6; i += 576) {
    int e = eidx[r0 + i / 6];
    lsum += expf(logits[(size_t)e * 6 + h6] - mloc);
  }
  __syncthreads();
  scratch[t] = lsum;
  __syncthreads();
  if (t < 6) {
    float s = 0.f;
    for (int g2 = t; g2 < 576; g2 += 6) s += scratch[g2];
    dh[t] = s;
  }
  __syncthreads();
  int h = t / 96;
  float mhv = mh[h];
  float rdh = 1.f / (dh[h] + 1e-16f);
  float acc = 0.f;
  for (int i = 0; i < d; i++) {
    int e = eidx[r0 + i];
    float a = expf(logits[(size_t)e * 6 + h] - mhv) * rdh;
    acc += a * xl[(size_t)src[e] * 576 + t];
  }
  __syncthreads();
  scratch[t] = acc;
  __syncthreads();
  if (t < 96) {
    float s = 0.f;
    for (int hh = 0; hh < 6; hh++) s += scratch[hh * 96 + t];
    s = s * (1.f / 6.f) + cbias[t];
    if (do_elu) s = (s > 0.f) ? s : expm1f(s);
    fin[t] = s;
  }
  __syncthreads();
  if (t == 0) {
    float s = 0.f, s2 = 0.f;
    for (int k = 0; k < 96; k++) { float v = fin[k]; s += v; s2 += v * v; }
    float mu = s / 96.f;
    float var = s2 / 96.f - mu * mu;
    red[0] = mu; red[1] = rsqrtf(var + 1e-5f);
  }
  __syncthreads();
  if (t < 96) {
    float y = (fin[t] - red[0]) * red[1] * lng[t] + lnb[t];
    x[(size_t)n * 96 + t] = x[(size_t)n * 96 + t] + y;
  }
}

// ---------------------------------------------------------------------------
// Predictor: per edge  ctx=[x[src],x[dst],emb] -> LN(relu)->.. -> scalar
// 16 edges per block, 128 threads
// ---------------------------------------------------------------------------
__global__ __launch_bounds__(128) void pred_kernel(
    const float* __restrict__ x, const float* __restrict__ emb,
    const int* __restrict__ src, const int* __restrict__ dst,
    const float* __restrict__ p1w, const float* __restrict__ p1b,
    const float* __restrict__ p1g, const float* __restrict__ p1be,
    const float* __restrict__ p2w, const float* __restrict__ p2b,
    const float* __restrict__ p2g, const float* __restrict__ p2be,
    const float* __restrict__ p3w, const float* __restrict__ p3b,
    float* __restrict__ out) {
  __shared__ float ctx[16][288];
  __shared__ float h1[16][128];
  __shared__ float h2[16][64];
  __shared__ float musig[16][2];
  int t = threadIdx.x;
  int e0 = blockIdx.x * 16;
  for (int idx = t; idx < 16 * 288; idx += 128) {
    int e = idx / 288, j = idx % 288;
    float v;
    if (j < 96) v = x[(size_t)src[e0 + e] * 96 + j];
    else if (j < 192) v = x[(size_t)dst[e0 + e] * 96 + (j - 96)];
    else v = emb[(size_t)(e0 + e) * 96 + (j - 192)];
    ctx[e][j] = v;
  }
  __syncthreads();
  float a1[16];
#pragma unroll
  for (int e = 0; e < 16; e++) a1[e] = 0.f;
  for (int k = 0; k < 288; k += 4) {
    float w0 = p1w[(k + 0) * 128 + t];
    float w1 = p1w[(k + 1) * 128 + t];
    float w2 = p1w[(k + 2) * 128 + t];
    float w3 = p1w[(k + 3) * 128 + t];
#pragma unroll
    for (int e = 0; e < 16; e++) {
      float4 cv = *(const float4*)&ctx[e][k];
      a1[e] += cv.x * w0 + cv.y * w1 + cv.z * w2 + cv.w * w3;
    }
  }
  float b1 = p1b[t];
#pragma unroll
  for (int e = 0; e < 16; e++) h1[e][t] = a1[e] + b1;
  __syncthreads();
  if (t < 16) {
    float s = 0.f, s2 = 0.f;
    for (int k = 0; k < 128; k++) { float v = h1[t][k]; s += v; s2 += v * v; }
    float mu = s / 128.f;
    float var = s2 / 128.f - mu * mu;
    musig[t][0] = mu; musig[t][1] = rsqrtf(var + 1e-5f);
  }
  __syncthreads();
  float g1 = p1g[t], be1 = p1be[t];
#pragma unroll
  for (int e = 0; e < 16; e++) {
    float v = (h1[e][t] - musig[e][0]) * musig[e][1] * g1 + be1;
    h1[e][t] = fmaxf(v, 0.f);
  }
  __syncthreads();
  if (t < 64) {
    float a2[16];
#pragma unroll
    for (int e = 0; e < 16; e++) a2[e] = 0.f;
    for (int k = 0; k < 128; k++) {
      float w = p2w[k * 64 + t];
#pragma unroll
      for (int e = 0; e < 16; e++) a2[e] += h1[e][k] * w;
    }
    float b2 = p2b[t];
#pragma unroll
    for (int e = 0; e < 16; e++) h2[e][t] = a2[e] + b2;
  }
  __syncthreads();
  if (t < 16) {
    float s = 0.f, s2 = 0.f;
    for (int k = 0; k < 64; k++) { float v = h2[t][k]; s += v; s2 += v * v; }
    float mu = s / 64.f;
    float var = s2 / 64.f - mu * mu;
    musig[t][0] = mu; musig[t][1] = rsqrtf(var + 1e-5f);
  }
  __syncthreads();
  if (t < 64) {
    float g2v = p2g[t], be2 = p2be[t];
#pragma unroll
    for (int e = 0; e < 16; e++) {
      float v = (h2[e][t] - musig[e][0]) * musig[e][1] * g2v + be2;
      h2[e][t] = fmaxf(v, 0.f);
    }
  }
  __syncthreads();
  if (t < 16) {
    float s = p3b[0];
    for (int k = 0; k < 64; k++) s += h2[t][k] * p3w[k];
    out[e0 + t] = s;
  }
}

// ---------------------------------------------------------------------------
static inline size_t alignup(size_t v) { return (v + 255) & ~(size_t)255; }

extern "C" void kernel_launch(void* const* d_in, const int* in_sizes, int n_in,
                              void* d_out, int out_size, void* d_ws, size_t ws_size,
                              hipStream_t stream) {
  const float* x_in      = (const float*)d_in[0];
  const float* edge_attr = (const float*)d_in[1];
  const int*   ei        = (const int*)d_in[2];
  const int* src = ei;
  const int* dst = ei + NE;
  const float* ne_w = (const float*)d_in[3];
  const float* ne_b = (const float*)d_in[4];
  const float* ne_g = (const float*)d_in[5];
  const float* ne_be = (const float*)d_in[6];
  const float* ee_w = (const float*)d_in[7];
  const float* ee_b = (const float*)d_in[8];
  const float* ee_g = (const float*)d_in[9];
  const float* ee_be = (const float*)d_in[10];
  const float* Wl = (const float*)d_in[11];
  const float* bl = (const float*)d_in[12];
  const float* Wr = (const float*)d_in[13];
  const float* br = (const float*)d_in[14];
  const float* We = (const float*)d_in[15];
  const float* attw = (const float*)d_in[16];
  const float* cbias = (const float*)d_in[17];
  const float* lng = (const float*)d_in[18];
  const float* lnb = (const float*)d_in[19];
  const float* p1w = (const float*)d_in[20];
  const float* p1b = (const float*)d_in[21];
  const float* p1g = (const float*)d_in[22];
  const float* p1be = (const float*)d_in[23];
  const float* p2w = (const float*)d_in[24];
  const float* p2b = (const float*)d_in[25];
  const float* p2g = (const float*)d_in[26];
  const float* p2be = (const float*)d_in[27];
  const float* p3w = (const float*)d_in[28];
  const float* p3b = (const float*)d_in[29];
  float* out = (float*)d_out;

  // workspace carve (aligned)
  char* w = (char*)d_ws;
  float* X    = (float*)w; w += alignup((size_t)NN * 96 * 4);
  float* EMB  = (float*)w; w += alignup((size_t)NE * 96 * 4);
  float* XL   = (float*)w; w += alignup((size_t)NN * 576 * 4);
  float* LOG  = (float*)w; w += alignup((size_t)NE * 6 * 4);
  unsigned short* EMBb = (unsigned short*)w; w += alignup((size_t)NE * 96 * 2);
  unsigned short* XLb  = (unsigned short*)w; w += alignup((size_t)NN * 576 * 2);
  unsigned short* XRb  = (unsigned short*)w; w += alignup((size_t)NN * 576 * 2);
  unsigned short* WeTb = (unsigned short*)w; w += alignup((size_t)3 * 576 * 96 * 2);
  int* deg    = (int*)w; w += alignup((size_t)(NN + 1) * 4);
  int* rowptr = (int*)w; w += alignup((size_t)(NN + 1) * 4);
  int* cursor = (int*)w; w += alignup((size_t)NN * 4);
  int* eidx   = (int*)w; w += alignup((size_t)NE * 4);

  // encoders (edge encoder also emits bf16 copy)
  encode_kernel<<<NN, 128, 0, stream>>>(x_in, 4, ne_w, ne_b, ne_g, ne_be, X, nullptr);
  encode_kernel<<<NE, 128, 0, stream>>>(edge_attr, 3, ee_w, ee_b, ee_g, ee_be, EMB, EMBb);
  convWeT_kernel<<<(3 * 576 * 96 + 255) / 256, 256, 0, stream>>>(We, WeTb);

  // CSR by dst
  hipMemsetAsync(deg, 0, (size_t)(NN + 1) * 4, stream);
  hist_kernel<<<(NE + 255) / 256, 256, 0, stream>>>(dst, deg);
  scan_kernel<<<1, 1024, 0, stream>>>(deg, rowptr, cursor);
  scatter_kernel<<<(NE + 255) / 256, 256, 0, stream>>>(dst, cursor, eidx);

  // 3 GATv2 layers
  for (int i = 0; i < 3; i++) {
    const float* Wl_i = Wl + (size_t)i * 96 * 576;
    const float* bl_i = bl + (size_t)i * 576;
    const float* Wr_i = Wr + (size_t)i * 96 * 576;
    const float* br_i = br + (size_t)i * 576;
    const unsigned short* WeT_i = WeTb + (size_t)i * 576 * 96;
    const float* aw_i = attw + (size_t)i * 576;
    const float* cb_i = cbias + (size_t)i * 96;
    const float* lg_i = lng + (size_t)i * 96;
    const float* lb_i = lnb + (size_t)i * 96;
    xlxr_kernel<<<NN / 8, 576, 0, stream>>>(X, Wl_i, bl_i, Wr_i, br_i, XL, XLb, XRb);
    logits_mfma_kernel<<<NE / 64, 256, 0, stream>>>(EMBb, WeT_i, aw_i, XLb, XRb,
                                                    src, dst, LOG);
    aggregate_kernel<<<NN, 576, 0, stream>>>(X, XL, LOG, rowptr, eidx, src,
                                             cb_i, lg_i, lb_i, (i < 2) ? 1 : 0);
  }

  // predictor
  pred_kernel<<<NE / 16, 128, 0, stream>>>(X, EMB, src, dst,
                                           p1w, p1b, p1g, p1be,
                                           p2w, p2b, p2g, p2be,
                                           p3w, p3b, out);
}

// Round 4
// 2609.947 us; speedup vs baseline: 1.9341x; 1.2240x over previous
//
#include <hip/hip_runtime.h>
#include <math.h>

#define NN 20000
#define NE 200000
#define HIDC 96
#define NHEAD 6
#define HC 576   // NHEAD*HIDC

typedef __attribute__((ext_vector_type(8))) short bf16x8;
typedef __attribute__((ext_vector_type(4))) float f32x4;

__device__ __forceinline__ unsigned short f2bf(float x) {
  union { float f; unsigned u; } c; c.f = x;
  unsigned r = c.u + 0x7FFF + ((c.u >> 16) & 1);
  return (unsigned short)(r >> 16);
}
__device__ __forceinline__ float bf2f(unsigned short u) {
  union { unsigned u; float f; } c; c.u = ((unsigned)u) << 16;
  return c.f;
}

// ---------------------------------------------------------------------------
// Encoder: out = relu(LN(in @ W + b))   in: [rows, D], W: [D,96]
// one row per block, 128 threads. fp32 and/or bf16 outputs (either nullable).
// ---------------------------------------------------------------------------
__global__ __launch_bounds__(128) void encode_kernel(
    const float* __restrict__ in, int D,
    const float* __restrict__ W, const float* __restrict__ b,
    const float* __restrict__ g, const float* __restrict__ beta,
    float* __restrict__ out, unsigned short* __restrict__ outb) {
  int row = blockIdx.x;
  int t = threadIdx.x;
  __shared__ float vin[8];
  __shared__ float part[2][2];
  __shared__ float red[2];
  if (t < D) vin[t] = in[row * D + t];
  __syncthreads();
  float v = 0.f;
  if (t < 96) {
    v = b[t];
    for (int k = 0; k < D; k++) v += vin[k] * W[k * 96 + t];
  }
  float ps = (t < 96) ? v : 0.f;
  float ps2 = (t < 96) ? v * v : 0.f;
#pragma unroll
  for (int off = 32; off > 0; off >>= 1) {
    ps += __shfl_down(ps, off);
    ps2 += __shfl_down(ps2, off);
  }
  if ((t & 63) == 0) { part[t >> 6][0] = ps; part[t >> 6][1] = ps2; }
  __syncthreads();
  if (t == 0) {
    float s = part[0][0] + part[1][0];
    float s2 = part[0][1] + part[1][1];
    float mu = s / 96.f;
    float var = s2 / 96.f - mu * mu;
    red[0] = mu; red[1] = rsqrtf(var + 1e-5f);
  }
  __syncthreads();
  if (t < 96) {
    float y = (v - red[0]) * red[1] * g[t] + beta[t];
    y = fmaxf(y, 0.f);
    if (out)  out[(size_t)row * 96 + t] = y;
    if (outb) outb[(size_t)row * 96 + t] = f2bf(y);
  }
}

// ---------------------------------------------------------------------------
// Weight prep: We [3][96][576] -> WeTb [3][576][96] bf16 ;
// p1w [288][128] -> p1wT [128][288] bf16 ; p2w [128][64] -> p2wT [64][128] bf16
// ---------------------------------------------------------------------------
__global__ void convW_kernel(const float* __restrict__ We,
                             unsigned short* __restrict__ WeTb,
                             const float* __restrict__ p1w,
                             unsigned short* __restrict__ p1wT,
                             const float* __restrict__ p2w,
                             unsigned short* __restrict__ p2wT) {
  int idx = blockIdx.x * 256 + threadIdx.x;
  if (idx < 3 * 576 * 96) {
    int l = idx / (576 * 96);
    int rem = idx % (576 * 96);
    int n = rem / 96, k = rem % 96;
    WeTb[idx] = f2bf(We[(size_t)l * 96 * 576 + (size_t)k * 576 + n]);
  }
  if (idx < 128 * 288) {
    int n = idx / 288, k = idx % 288;
    p1wT[idx] = f2bf(p1w[(size_t)k * 128 + n]);
  }
  if (idx < 64 * 128) {
    int n = idx / 128, k = idx % 128;
    p2wT[idx] = f2bf(p2w[(size_t)k * 64 + n]);
  }
}

// ---------------------------------------------------------------------------
// CSR build by dst
// ---------------------------------------------------------------------------
__global__ void hist_kernel(const int* __restrict__ dst, int* __restrict__ deg) {
  int e = blockIdx.x * blockDim.x + threadIdx.x;
  if (e < NE) atomicAdd(&deg[dst[e]], 1);
}

__global__ __launch_bounds__(1024) void scan_kernel(
    const int* __restrict__ deg, int* __restrict__ rowptr, int* __restrict__ cursor) {
  __shared__ int buf[1024];
  __shared__ int carry_s;
  int t = threadIdx.x;
  if (t == 0) carry_s = 0;
  __syncthreads();
  for (int base = 0; base < NN; base += 1024) {
    int i = base + t;
    int v = (i < NN) ? deg[i] : 0;
    buf[t] = v;
    __syncthreads();
    for (int off = 1; off < 1024; off <<= 1) {
      int add = (t >= off) ? buf[t - off] : 0;
      __syncthreads();
      buf[t] += add;
      __syncthreads();
    }
    int carry = carry_s;
    int excl = carry + buf[t] - v;
    if (i < NN) { rowptr[i] = excl; cursor[i] = excl; }
    __syncthreads();
    if (t == 1023) carry_s = carry + buf[1023];
    __syncthreads();
  }
  if (t == 0) rowptr[NN] = NE;
}

__global__ void scatter_kernel(const int* __restrict__ dst,
                               int* __restrict__ cursor, int* __restrict__ eidx) {
  int e = blockIdx.x * blockDim.x + threadIdx.x;
  if (e < NE) {
    int p = atomicAdd(&cursor[dst[e]], 1);
    eidx[p] = e;
  }
}

// ---------------------------------------------------------------------------
// xl = x@Wl+bl (fp32 + bf16 copies), xr = x@Wr+br (bf16 only)
// 8 nodes per block, 576 threads = one col each
// ---------------------------------------------------------------------------
__global__ __launch_bounds__(576) void xlxr_kernel(
    const float* __restrict__ x,
    const float* __restrict__ Wl, const float* __restrict__ bl,
    const float* __restrict__ Wr, const float* __restrict__ br,
    float* __restrict__ xl, unsigned short* __restrict__ xlb,
    unsigned short* __restrict__ xrb) {
  __shared__ float xs[8][96];
  int t = threadIdx.x;
  int n0 = blockIdx.x * 8;
  for (int idx = t; idx < 8 * 96; idx += 576)
    xs[idx / 96][idx % 96] = x[(size_t)(n0 + idx / 96) * 96 + idx % 96];
  __syncthreads();
  float aL[8], aR[8];
#pragma unroll
  for (int e = 0; e < 8; e++) { aL[e] = 0.f; aR[e] = 0.f; }
  for (int k = 0; k < 96; k += 4) {
    float wl0 = Wl[(k + 0) * 576 + t], wr0 = Wr[(k + 0) * 576 + t];
    float wl1 = Wl[(k + 1) * 576 + t], wr1 = Wr[(k + 1) * 576 + t];
    float wl2 = Wl[(k + 2) * 576 + t], wr2 = Wr[(k + 2) * 576 + t];
    float wl3 = Wl[(k + 3) * 576 + t], wr3 = Wr[(k + 3) * 576 + t];
#pragma unroll
    for (int e = 0; e < 8; e++) {
      float4 xv = *(const float4*)&xs[e][k];
      aL[e] += xv.x * wl0 + xv.y * wl1 + xv.z * wl2 + xv.w * wl3;
      aR[e] += xv.x * wr0 + xv.y * wr1 + xv.z * wr2 + xv.w * wr3;
    }
  }
  float bL = bl[t], bR = br[t];
#pragma unroll
  for (int e = 0; e < 8; e++) {
    float vl = aL[e] + bL;
    float vr = aR[e] + bR;
    xl[(size_t)(n0 + e) * 576 + t] = vl;
    xlb[(size_t)(n0 + e) * 576 + t] = f2bf(vl);
    xrb[(size_t)(n0 + e) * 576 + t] = f2bf(vr);
  }
}

// ---------------------------------------------------------------------------
// Fused logits via MFMA bf16 (verified layout from R3)
// ---------------------------------------------------------------------------
__global__ __launch_bounds__(256) void logits_mfma_kernel(
    const unsigned short* __restrict__ EMBb,   // [NE][96]
    const unsigned short* __restrict__ WeTb,   // [576][96]
    const float* __restrict__ attw,            // [576]
    const unsigned short* __restrict__ XLb,    // [NN][576]
    const unsigned short* __restrict__ XRb,    // [NN][576]
    const int* __restrict__ src, const int* __restrict__ dst,
    float* __restrict__ logits) {
  __shared__ int sd[64][2];
  int t = threadIdx.x;
  int e0 = blockIdx.x * 64;
  if (t < 128) {
    int e = t >> 1;
    sd[e][t & 1] = (t & 1) ? dst[e0 + e] : src[e0 + e];
  }
  __syncthreads();
  int wave = t >> 6;
  int lane = t & 63;
  int l15 = lane & 15;
  int quad = lane >> 4;
  const unsigned short* arow = &EMBb[(size_t)(e0 + wave * 16 + l15) * 96 + quad * 8];
  bf16x8 a0 = *(const bf16x8*)&arow[0];
  bf16x8 a1 = *(const bf16x8*)&arow[32];
  bf16x8 a2 = *(const bf16x8*)&arow[64];
  float part[4][6];
#pragma unroll
  for (int r = 0; r < 4; r++)
#pragma unroll
    for (int h = 0; h < 6; h++) part[r][h] = 0.f;

  for (int tt = 0; tt < 36; tt++) {
    int n0 = tt * 16;
    int col = n0 + l15;
    const unsigned short* brow = &WeTb[(size_t)col * 96 + quad * 8];
    bf16x8 b0 = *(const bf16x8*)&brow[0];
    bf16x8 b1 = *(const bf16x8*)&brow[32];
    bf16x8 b2 = *(const bf16x8*)&brow[64];
    f32x4 acc = {0.f, 0.f, 0.f, 0.f};
    acc = __builtin_amdgcn_mfma_f32_16x16x32_bf16(a0, b0, acc, 0, 0, 0);
    acc = __builtin_amdgcn_mfma_f32_16x16x32_bf16(a1, b1, acc, 0, 0, 0);
    acc = __builtin_amdgcn_mfma_f32_16x16x32_bf16(a2, b2, acc, 0, 0, 0);
    float aw = attw[col];
    int hh = tt / 6;
#pragma unroll
    for (int r = 0; r < 4; r++) {
      int el = wave * 16 + quad * 4 + r;
      float xlv = bf2f(XLb[(size_t)sd[el][0] * 576 + col]);
      float xrv = bf2f(XRb[(size_t)sd[el][1] * 576 + col]);
      float v = acc[r] + xlv + xrv;
      v = (v > 0.f) ? v : 0.2f * v;
      part[r][hh] += v * aw;
    }
  }
#pragma unroll
  for (int r = 0; r < 4; r++)
#pragma unroll
    for (int h = 0; h < 6; h++) {
      float p = part[r][h];
      p += __shfl_xor(p, 1);
      p += __shfl_xor(p, 2);
      p += __shfl_xor(p, 4);
      p += __shfl_xor(p, 8);
      part[r][h] = p;
    }
  if (l15 == 0) {
    int el = e0 + wave * 16 + quad * 4;
#pragma unroll
    for (int r = 0; r < 4; r++)
#pragma unroll
      for (int h = 0; h < 6; h++)
        logits[(size_t)(el + r) * 6 + h] = part[r][h];
  }
}

// ---------------------------------------------------------------------------
// Per-dst-node softmax + aggregate + head-mean + elu + LN + residual.
// Also emits bf16 copy of updated x (for predictor ctx gathers).
// ---------------------------------------------------------------------------
__global__ __launch_bounds__(576) void aggregate_kernel(
    float* __restrict__ x, unsigned short* __restrict__ xb,
    const float* __restrict__ xl,
    const float* __restrict__ logits, const int* __restrict__ rowptr,
    const int* __restrict__ eidx, const int* __restrict__ src,
    const float* __restrict__ cbias, const float* __restrict__ lng,
    const float* __restrict__ lnb, int do_elu) {
  int n = blockIdx.x;
  int t = threadIdx.x;
  int r0 = rowptr[n], r1 = rowptr[n + 1];
  int d = r1 - r0;
  __shared__ float mh[6], dh[6];
  __shared__ float scratch[576];
  __shared__ float fin[96];
  __shared__ float red[2];
  int h6 = t % 6;
  float lmax = -1e30f;
  for (int i = t; i < d * 6; i += 576) {
    int e = eidx[r0 + i / 6];
    lmax = fmaxf(lmax, logits[(size_t)e * 6 + h6]);
  }
  scratch[t] = lmax;
  __syncthreads();
  if (t < 6) {
    float m = -1e30f;
    for (int g2 = t; g2 < 576; g2 += 6) m = fmaxf(m, scratch[g2]);
    mh[t] = m;
  }
  __syncthreads();
  float lsum = 0.f;
  float mloc = mh[h6];
  for (int i = t; i < d * 6; i += 576) {
    int e = eidx[r0 + i / 6];
    lsum += expf(logits[(size_t)e * 6 + h6] - mloc);
  }
  __syncthreads();
  scratch[t] = lsum;
  __syncthreads();
  if (t < 6) {
    float s = 0.f;
    for (int g2 = t; g2 < 576; g2 += 6) s += scratch[g2];
    dh[t] = s;
  }
  __syncthreads();
  int h = t / 96;
  float mhv = mh[h];
  float rdh = 1.f / (dh[h] + 1e-16f);
  float acc = 0.f;
  for (int i = 0; i < d; i++) {
    int e = eidx[r0 + i];
    float a = expf(logits[(size_t)e * 6 + h] - mhv) * rdh;
    acc += a * xl[(size_t)src[e] * 576 + t];
  }
  __syncthreads();
  scratch[t] = acc;
  __syncthreads();
  if (t < 96) {
    float s = 0.f;
    for (int hh = 0; hh < 6; hh++) s += scratch[hh * 96 + t];
    s = s * (1.f / 6.f) + cbias[t];
    if (do_elu) s = (s > 0.f) ? s : expm1f(s);
    fin[t] = s;
  }
  __syncthreads();
  if (t == 0) {
    float s = 0.f, s2 = 0.f;
    for (int k = 0; k < 96; k++) { float v = fin[k]; s += v; s2 += v * v; }
    float mu = s / 96.f;
    float var = s2 / 96.f - mu * mu;
    red[0] = mu; red[1] = rsqrtf(var + 1e-5f);
  }
  __syncthreads();
  if (t < 96) {
    float y = (fin[t] - red[0]) * red[1] * lng[t] + lnb[t];
    float nv = x[(size_t)n * 96 + t] + y;
    x[(size_t)n * 96 + t] = nv;
    xb[(size_t)n * 96 + t] = f2bf(nv);
  }
}

// ---------------------------------------------------------------------------
// Predictor via MFMA: ctx(bf16 frags, direct gather) -> p1 (8 N-tiles x 9 K)
// -> LN(shfl) -> relu -> LDS transpose -> p2 (4x4) -> LN -> relu -> p3 dot.
// 256 thr = 4 waves x 16 edges.
// ---------------------------------------------------------------------------
__global__ __launch_bounds__(256) void pred_mfma_kernel(
    const unsigned short* __restrict__ Xb,     // [NN][96]
    const unsigned short* __restrict__ EMBb,   // [NE][96]
    const int* __restrict__ src, const int* __restrict__ dst,
    const unsigned short* __restrict__ p1wT,   // [128][288]
    const float* __restrict__ p1b, const float* __restrict__ p1g,
    const float* __restrict__ p1be,
    const unsigned short* __restrict__ p2wT,   // [64][128]
    const float* __restrict__ p2b, const float* __restrict__ p2g,
    const float* __restrict__ p2be,
    const float* __restrict__ p3w, const float* __restrict__ p3b,
    float* __restrict__ out) {
  __shared__ unsigned short h1s[4][16][136];   // per-wave, padded (16B-aligned rows)
  int t = threadIdx.x;
  int wave = t >> 6, lane = t & 63;
  int l15 = lane & 15, quad = lane >> 4;
  int ebase = blockIdx.x * 64 + wave * 16;
  int erow = ebase + l15;
  int sN = src[erow], dN = dst[erow];

  // A fragments: ctx row = [x[src] | x[dst] | emb], 9 K-chunks of 32
  bf16x8 A[9];
  const unsigned short* xs = &Xb[(size_t)sN * 96 + quad * 8];
  const unsigned short* xd = &Xb[(size_t)dN * 96 + quad * 8];
  const unsigned short* em = &EMBb[(size_t)erow * 96 + quad * 8];
#pragma unroll
  for (int c = 0; c < 3; c++) {
    A[c]     = *(const bf16x8*)&xs[c * 32];
    A[c + 3] = *(const bf16x8*)&xd[c * 32];
    A[c + 6] = *(const bf16x8*)&em[c * 32];
  }

  // GEMM1: h1[16][128]
  f32x4 C1[8];
#pragma unroll
  for (int nt = 0; nt < 8; nt++) {
    f32x4 acc = {0.f, 0.f, 0.f, 0.f};
    const unsigned short* bp = &p1wT[(size_t)(nt * 16 + l15) * 288 + quad * 8];
#pragma unroll
    for (int c = 0; c < 9; c++) {
      bf16x8 B = *(const bf16x8*)&bp[c * 32];
      acc = __builtin_amdgcn_mfma_f32_16x16x32_bf16(A[c], B, acc, 0, 0, 0);
    }
    float bias = p1b[nt * 16 + l15];
    acc[0] += bias; acc[1] += bias; acc[2] += bias; acc[3] += bias;
    C1[nt] = acc;
  }

  // LN over 128 cols (rows = quad*4+r), shfl over the 16 lanes of the quad
  float mu1[4], rs1[4];
#pragma unroll
  for (int r = 0; r < 4; r++) {
    float s = 0.f, s2 = 0.f;
#pragma unroll
    for (int nt = 0; nt < 8; nt++) { float v = C1[nt][r]; s += v; s2 += v * v; }
    s += __shfl_xor(s, 1);  s += __shfl_xor(s, 2);
    s += __shfl_xor(s, 4);  s += __shfl_xor(s, 8);
    s2 += __shfl_xor(s2, 1); s2 += __shfl_xor(s2, 2);
    s2 += __shfl_xor(s2, 4); s2 += __shfl_xor(s2, 8);
    float mu = s * (1.f / 128.f);
    float var = s2 * (1.f / 128.f) - mu * mu;
    mu1[r] = mu;
    rs1[r] = rsqrtf(var + 1e-5f);
  }
  // normalize + relu + bf16 -> LDS (C-layout -> A-layout transpose)
#pragma unroll
  for (int nt = 0; nt < 8; nt++) {
    float g = p1g[nt * 16 + l15], be = p1be[nt * 16 + l15];
#pragma unroll
    for (int r = 0; r < 4; r++) {
      float v = (C1[nt][r] - mu1[r]) * rs1[r] * g + be;
      v = fmaxf(v, 0.f);
      h1s[wave][quad * 4 + r][nt * 16 + l15] = f2bf(v);
    }
  }
  __syncthreads();

  // GEMM2: h2[16][64]
  f32x4 C2[4];
#pragma unroll
  for (int nt = 0; nt < 4; nt++) {
    f32x4 acc = {0.f, 0.f, 0.f, 0.f};
    const unsigned short* bp = &p2wT[(size_t)(nt * 16 + l15) * 128 + quad * 8];
#pragma unroll
    for (int c = 0; c < 4; c++) {
      bf16x8 Af = *(const bf16x8*)&h1s[wave][l15][c * 32 + quad * 8];
      bf16x8 B = *(const bf16x8*)&bp[c * 32];
      acc = __builtin_amdgcn_mfma_f32_16x16x32_bf16(Af, B, acc, 0, 0, 0);
    }
    float bias = p2b[nt * 16 + l15];
    acc[0] += bias; acc[1] += bias; acc[2] += bias; acc[3] += bias;
    C2[nt] = acc;
  }

  // LN over 64 cols
  float mu2[4], rs2[4];
#pragma unroll
  for (int r = 0; r < 4; r++) {
    float s = 0.f, s2 = 0.f;
#pragma unroll
    for (int nt = 0; nt < 4; nt++) { float v = C2[nt][r]; s += v; s2 += v * v; }
    s += __shfl_xor(s, 1);  s += __shfl_xor(s, 2);
    s += __shfl_xor(s, 4);  s += __shfl_xor(s, 8);
    s2 += __shfl_xor(s2, 1); s2 += __shfl_xor(s2, 2);
    s2 += __shfl_xor(s2, 4); s2 += __shfl_xor(s2, 8);
    float mu = s * (1.f / 64.f);
    float var = s2 * (1.f / 64.f) - mu * mu;
    mu2[r] = mu;
    rs2[r] = rsqrtf(var + 1e-5f);
  }

  // p3 dot: out = relu(LN(h2)) @ p3w + p3b
  float partial[4] = {0.f, 0.f, 0.f, 0.f};
#pragma unroll
  for (int nt = 0; nt < 4; nt++) {
    float g = p2g[nt * 16 + l15], be = p2be[nt * 16 + l15];
    float pw = p3w[nt * 16 + l15];
#pragma unroll
    for (int r = 0; r < 4; r++) {
      float v = (C2[nt][r] - mu2[r]) * rs2[r] * g + be;
      v = fmaxf(v, 0.f);
      partial[r] += v * pw;
    }
  }
#pragma unroll
  for (int r = 0; r < 4; r++) {
    float p = partial[r];
    p += __shfl_xor(p, 1);
    p += __shfl_xor(p, 2);
    p += __shfl_xor(p, 4);
    p += __shfl_xor(p, 8);
    partial[r] = p;
  }
  if (l15 == 0) {
    float b3 = p3b[0];
#pragma unroll
    for (int r = 0; r < 4; r++)
      out[ebase + quad * 4 + r] = partial[r] + b3;
  }
}

// ---------------------------------------------------------------------------
static inline size_t alignup(size_t v) { return (v + 255) & ~(size_t)255; }

extern "C" void kernel_launch(void* const* d_in, const int* in_sizes, int n_in,
                              void* d_out, int out_size, void* d_ws, size_t ws_size,
                              hipStream_t stream) {
  const float* x_in      = (const float*)d_in[0];
  const float* edge_attr = (const float*)d_in[1];
  const int*   ei        = (const int*)d_in[2];
  const int* src = ei;
  const int* dst = ei + NE;
  const float* ne_w = (const float*)d_in[3];
  const float* ne_b = (const float*)d_in[4];
  const float* ne_g = (const float*)d_in[5];
  const float* ne_be = (const float*)d_in[6];
  const float* ee_w = (const float*)d_in[7];
  const float* ee_b = (const float*)d_in[8];
  const float* ee_g = (const float*)d_in[9];
  const float* ee_be = (const float*)d_in[10];
  const float* Wl = (const float*)d_in[11];
  const float* bl = (const float*)d_in[12];
  const float* Wr = (const float*)d_in[13];
  const float* br = (const float*)d_in[14];
  const float* We = (const float*)d_in[15];
  const float* attw = (const float*)d_in[16];
  const float* cbias = (const float*)d_in[17];
  const float* lng = (const float*)d_in[18];
  const float* lnb = (const float*)d_in[19];
  const float* p1w = (const float*)d_in[20];
  const float* p1b = (const float*)d_in[21];
  const float* p1g = (const float*)d_in[22];
  const float* p1be = (const float*)d_in[23];
  const float* p2w = (const float*)d_in[24];
  const float* p2b = (const float*)d_in[25];
  const float* p2g = (const float*)d_in[26];
  const float* p2be = (const float*)d_in[27];
  const float* p3w = (const float*)d_in[28];
  const float* p3b = (const float*)d_in[29];
  float* out = (float*)d_out;

  // workspace carve (aligned)
  char* w = (char*)d_ws;
  float* X    = (float*)w; w += alignup((size_t)NN * 96 * 4);
  float* XL   = (float*)w; w += alignup((size_t)NN * 576 * 4);
  float* LOG  = (float*)w; w += alignup((size_t)NE * 6 * 4);
  unsigned short* EMBb = (unsigned short*)w; w += alignup((size_t)NE * 96 * 2);
  unsigned short* XLb  = (unsigned short*)w; w += alignup((size_t)NN * 576 * 2);
  unsigned short* XRb  = (unsigned short*)w; w += alignup((size_t)NN * 576 * 2);
  unsigned short* Xb   = (unsigned short*)w; w += alignup((size_t)NN * 96 * 2);
  unsigned short* WeTb = (unsigned short*)w; w += alignup((size_t)3 * 576 * 96 * 2);
  unsigned short* p1wT = (unsigned short*)w; w += alignup((size_t)128 * 288 * 2);
  unsigned short* p2wT = (unsigned short*)w; w += alignup((size_t)64 * 128 * 2);
  int* deg    = (int*)w; w += alignup((size_t)(NN + 1) * 4);
  int* rowptr = (int*)w; w += alignup((size_t)(NN + 1) * 4);
  int* cursor = (int*)w; w += alignup((size_t)NN * 4);
  int* eidx   = (int*)w; w += alignup((size_t)NE * 4);

  // encoders + weight prep
  encode_kernel<<<NN, 128, 0, stream>>>(x_in, 4, ne_w, ne_b, ne_g, ne_be, X, nullptr);
  encode_kernel<<<NE, 128, 0, stream>>>(edge_attr, 3, ee_w, ee_b, ee_g, ee_be,
                                        nullptr, EMBb);
  convW_kernel<<<(3 * 576 * 96 + 255) / 256, 256, 0, stream>>>(We, WeTb, p1w, p1wT,
                                                               p2w, p2wT);

  // CSR by dst
  hipMemsetAsync(deg, 0, (size_t)(NN + 1) * 4, stream);
  hist_kernel<<<(NE + 255) / 256, 256, 0, stream>>>(dst, deg);
  scan_kernel<<<1, 1024, 0, stream>>>(deg, rowptr, cursor);
  scatter_kernel<<<(NE + 255) / 256, 256, 0, stream>>>(dst, cursor, eidx);

  // 3 GATv2 layers
  for (int i = 0; i < 3; i++) {
    const float* Wl_i = Wl + (size_t)i * 96 * 576;
    const float* bl_i = bl + (size_t)i * 576;
    const float* Wr_i = Wr + (size_t)i * 96 * 576;
    const float* br_i = br + (size_t)i * 576;
    const unsigned short* WeT_i = WeTb + (size_t)i * 576 * 96;
    const float* aw_i = attw + (size_t)i * 576;
    const float* cb_i = cbias + (size_t)i * 96;
    const float* lg_i = lng + (size_t)i * 96;
    const float* lb_i = lnb + (size_t)i * 96;
    xlxr_kernel<<<NN / 8, 576, 0, stream>>>(X, Wl_i, bl_i, Wr_i, br_i, XL, XLb, XRb);
    logits_mfma_kernel<<<NE / 64, 256, 0, stream>>>(EMBb, WeT_i, aw_i, XLb, XRb,
                                                    src, dst, LOG);
    aggregate_kernel<<<NN, 576, 0, stream>>>(X, Xb, XL, LOG, rowptr, eidx, src,
                                             cb_i, lg_i, lb_i, (i < 2) ? 1 : 0);
  }

  // predictor (MFMA)
  pred_mfma_kernel<<<NE / 64, 256, 0, stream>>>(Xb, EMBb, src, dst,
                                                p1wT, p1b, p1g, p1be,
                                                p2wT, p2b, p2g, p2be,
                                                p3w, p3b, out);
}

// Round 5
// 1853.299 us; speedup vs baseline: 2.7237x; 1.4083x over previous
//
#include <hip/hip_runtime.h>
#include <math.h>

#define NN 20000
#define NE 200000
#define HIDC 96
#define NHEAD 6
#define HC 576   // NHEAD*HIDC

typedef __attribute__((ext_vector_type(8))) short bf16x8;
typedef __attribute__((ext_vector_type(4))) float f32x4;

__device__ __forceinline__ unsigned short f2bf(float x) {
  union { float f; unsigned u; } c; c.f = x;
  unsigned r = c.u + 0x7FFF + ((c.u >> 16) & 1);
  return (unsigned short)(r >> 16);
}
__device__ __forceinline__ float bf2f(unsigned short u) {
  union { unsigned u; float f; } c; c.u = ((unsigned)u) << 16;
  return c.f;
}

// ---------------------------------------------------------------------------
// Encoder: out = relu(LN(in @ W + b))   in: [rows, D], W: [D,96]
// one row per block, 128 threads. fp32 and/or bf16 outputs (either nullable).
// ---------------------------------------------------------------------------
__global__ __launch_bounds__(128) void encode_kernel(
    const float* __restrict__ in, int D,
    const float* __restrict__ W, const float* __restrict__ b,
    const float* __restrict__ g, const float* __restrict__ beta,
    float* __restrict__ out, unsigned short* __restrict__ outb) {
  int row = blockIdx.x;
  int t = threadIdx.x;
  __shared__ float vin[8];
  __shared__ float part[2][2];
  __shared__ float red[2];
  if (t < D) vin[t] = in[row * D + t];
  __syncthreads();
  float v = 0.f;
  if (t < 96) {
    v = b[t];
    for (int k = 0; k < D; k++) v += vin[k] * W[k * 96 + t];
  }
  float ps = (t < 96) ? v : 0.f;
  float ps2 = (t < 96) ? v * v : 0.f;
#pragma unroll
  for (int off = 32; off > 0; off >>= 1) {
    ps += __shfl_down(ps, off);
    ps2 += __shfl_down(ps2, off);
  }
  if ((t & 63) == 0) { part[t >> 6][0] = ps; part[t >> 6][1] = ps2; }
  __syncthreads();
  if (t == 0) {
    float s = part[0][0] + part[1][0];
    float s2 = part[0][1] + part[1][1];
    float mu = s / 96.f;
    float var = s2 / 96.f - mu * mu;
    red[0] = mu; red[1] = rsqrtf(var + 1e-5f);
  }
  __syncthreads();
  if (t < 96) {
    float y = (v - red[0]) * red[1] * g[t] + beta[t];
    y = fmaxf(y, 0.f);
    if (out)  out[(size_t)row * 96 + t] = y;
    if (outb) outb[(size_t)row * 96 + t] = f2bf(y);
  }
}

// ---------------------------------------------------------------------------
// Weight prep: We [3][96][576] -> WeTb [3][576][96] bf16 ;
// p1w [288][128] -> p1wT [128][288] bf16 ; p2w [128][64] -> p2wT [64][128] bf16
// ---------------------------------------------------------------------------
__global__ void convW_kernel(const float* __restrict__ We,
                             unsigned short* __restrict__ WeTb,
                             const float* __restrict__ p1w,
                             unsigned short* __restrict__ p1wT,
                             const float* __restrict__ p2w,
                             unsigned short* __restrict__ p2wT) {
  int idx = blockIdx.x * 256 + threadIdx.x;
  if (idx < 3 * 576 * 96) {
    int l = idx / (576 * 96);
    int rem = idx % (576 * 96);
    int n = rem / 96, k = rem % 96;
    WeTb[idx] = f2bf(We[(size_t)l * 96 * 576 + (size_t)k * 576 + n]);
  }
  if (idx < 128 * 288) {
    int n = idx / 288, k = idx % 288;
    p1wT[idx] = f2bf(p1w[(size_t)k * 128 + n]);
  }
  if (idx < 64 * 128) {
    int n = idx / 128, k = idx % 128;
    p2wT[idx] = f2bf(p2w[(size_t)k * 64 + n]);
  }
}

// ---------------------------------------------------------------------------
// CSR build by dst
// ---------------------------------------------------------------------------
__global__ void hist_kernel(const int* __restrict__ dst, int* __restrict__ deg) {
  int e = blockIdx.x * blockDim.x + threadIdx.x;
  if (e < NE) atomicAdd(&deg[dst[e]], 1);
}

__global__ __launch_bounds__(1024) void scan_kernel(
    const int* __restrict__ deg, int* __restrict__ rowptr, int* __restrict__ cursor) {
  __shared__ int buf[1024];
  __shared__ int carry_s;
  int t = threadIdx.x;
  if (t == 0) carry_s = 0;
  __syncthreads();
  for (int base = 0; base < NN; base += 1024) {
    int i = base + t;
    int v = (i < NN) ? deg[i] : 0;
    buf[t] = v;
    __syncthreads();
    for (int off = 1; off < 1024; off <<= 1) {
      int add = (t >= off) ? buf[t - off] : 0;
      __syncthreads();
      buf[t] += add;
      __syncthreads();
    }
    int carry = carry_s;
    int excl = carry + buf[t] - v;
    if (i < NN) { rowptr[i] = excl; cursor[i] = excl; }
    __syncthreads();
    if (t == 1023) carry_s = carry + buf[1023];
    __syncthreads();
  }
  if (t == 0) rowptr[NN] = NE;
}

__global__ void scatter_kernel(const int* __restrict__ dst,
                               int* __restrict__ cursor, int* __restrict__ eidx) {
  int e = blockIdx.x * blockDim.x + threadIdx.x;
  if (e < NE) {
    int p = atomicAdd(&cursor[dst[e]], 1);
    eidx[p] = e;
  }
}

// ---------------------------------------------------------------------------
// xl = x@Wl+bl, xr = x@Wr+br   (bf16 outputs only)
// 8 nodes per block, 576 threads = one col each
// ---------------------------------------------------------------------------
__global__ __launch_bounds__(576) void xlxr_kernel(
    const float* __restrict__ x,
    const float* __restrict__ Wl, const float* __restrict__ bl,
    const float* __restrict__ Wr, const float* __restrict__ br,
    unsigned short* __restrict__ xlb, unsigned short* __restrict__ xrb) {
  __shared__ float xs[8][96];
  int t = threadIdx.x;
  int n0 = blockIdx.x * 8;
  for (int idx = t; idx < 8 * 96; idx += 576)
    xs[idx / 96][idx % 96] = x[(size_t)(n0 + idx / 96) * 96 + idx % 96];
  __syncthreads();
  float aL[8], aR[8];
#pragma unroll
  for (int e = 0; e < 8; e++) { aL[e] = 0.f; aR[e] = 0.f; }
  for (int k = 0; k < 96; k += 4) {
    float wl0 = Wl[(k + 0) * 576 + t], wr0 = Wr[(k + 0) * 576 + t];
    float wl1 = Wl[(k + 1) * 576 + t], wr1 = Wr[(k + 1) * 576 + t];
    float wl2 = Wl[(k + 2) * 576 + t], wr2 = Wr[(k + 2) * 576 + t];
    float wl3 = Wl[(k + 3) * 576 + t], wr3 = Wr[(k + 3) * 576 + t];
#pragma unroll
    for (int e = 0; e < 8; e++) {
      float4 xv = *(const float4*)&xs[e][k];
      aL[e] += xv.x * wl0 + xv.y * wl1 + xv.z * wl2 + xv.w * wl3;
      aR[e] += xv.x * wr0 + xv.y * wr1 + xv.z * wr2 + xv.w * wr3;
    }
  }
  float bL = bl[t], bR = br[t];
#pragma unroll
  for (int e = 0; e < 8; e++) {
    xlb[(size_t)(n0 + e) * 576 + t] = f2bf(aL[e] + bL);
    xrb[(size_t)(n0 + e) * 576 + t] = f2bf(aR[e] + bR);
  }
}

// ---------------------------------------------------------------------------
// Fused logits via MFMA bf16 (verified layout from R3)
// ---------------------------------------------------------------------------
__global__ __launch_bounds__(256) void logits_mfma_kernel(
    const unsigned short* __restrict__ EMBb,   // [NE][96]
    const unsigned short* __restrict__ WeTb,   // [576][96]
    const float* __restrict__ attw,            // [576]
    const unsigned short* __restrict__ XLb,    // [NN][576]
    const unsigned short* __restrict__ XRb,    // [NN][576]
    const int* __restrict__ src, const int* __restrict__ dst,
    float* __restrict__ logits) {
  __shared__ int sd[64][2];
  int t = threadIdx.x;
  int e0 = blockIdx.x * 64;
  if (t < 128) {
    int e = t >> 1;
    sd[e][t & 1] = (t & 1) ? dst[e0 + e] : src[e0 + e];
  }
  __syncthreads();
  int wave = t >> 6;
  int lane = t & 63;
  int l15 = lane & 15;
  int quad = lane >> 4;
  const unsigned short* arow = &EMBb[(size_t)(e0 + wave * 16 + l15) * 96 + quad * 8];
  bf16x8 a0 = *(const bf16x8*)&arow[0];
  bf16x8 a1 = *(const bf16x8*)&arow[32];
  bf16x8 a2 = *(const bf16x8*)&arow[64];
  float part[4][6];
#pragma unroll
  for (int r = 0; r < 4; r++)
#pragma unroll
    for (int h = 0; h < 6; h++) part[r][h] = 0.f;

  for (int tt = 0; tt < 36; tt++) {
    int n0 = tt * 16;
    int col = n0 + l15;
    const unsigned short* brow = &WeTb[(size_t)col * 96 + quad * 8];
    bf16x8 b0 = *(const bf16x8*)&brow[0];
    bf16x8 b1 = *(const bf16x8*)&brow[32];
    bf16x8 b2 = *(const bf16x8*)&brow[64];
    f32x4 acc = {0.f, 0.f, 0.f, 0.f};
    acc = __builtin_amdgcn_mfma_f32_16x16x32_bf16(a0, b0, acc, 0, 0, 0);
    acc = __builtin_amdgcn_mfma_f32_16x16x32_bf16(a1, b1, acc, 0, 0, 0);
    acc = __builtin_amdgcn_mfma_f32_16x16x32_bf16(a2, b2, acc, 0, 0, 0);
    float aw = attw[col];
    int hh = tt / 6;
#pragma unroll
    for (int r = 0; r < 4; r++) {
      int el = wave * 16 + quad * 4 + r;
      float xlv = bf2f(XLb[(size_t)sd[el][0] * 576 + col]);
      float xrv = bf2f(XRb[(size_t)sd[el][1] * 576 + col]);
      float v = acc[r] + xlv + xrv;
      v = (v > 0.f) ? v : 0.2f * v;
      part[r][hh] += v * aw;
    }
  }
#pragma unroll
  for (int r = 0; r < 4; r++)
#pragma unroll
    for (int h = 0; h < 6; h++) {
      float p = part[r][h];
      p += __shfl_xor(p, 1);
      p += __shfl_xor(p, 2);
      p += __shfl_xor(p, 4);
      p += __shfl_xor(p, 8);
      part[r][h] = p;
    }
  if (l15 == 0) {
    int el = e0 + wave * 16 + quad * 4;
#pragma unroll
    for (int r = 0; r < 4; r++)
#pragma unroll
      for (int h = 0; h < 6; h++)
        logits[(size_t)(el + r) * 6 + h] = part[r][h];
  }
}

// ---------------------------------------------------------------------------
// Aggregate v2: single-pass online softmax + weighted bf16 gather.
// One node per block, 576 threads (t = h*96 + c). Chunks of 64 edges staged
// in LDS (src + per-head exp weights), then a 4x-unrolled gather-FMA loop.
// Epilogue: head mean + cbias + elu + LN + residual; emits fp32 & bf16 x.
// ---------------------------------------------------------------------------
__global__ __launch_bounds__(576) void aggregate_kernel(
    float* __restrict__ x, unsigned short* __restrict__ xb,
    const unsigned short* __restrict__ XLb,
    const float* __restrict__ logits, const int* __restrict__ rowptr,
    const int* __restrict__ eidx, const int* __restrict__ src,
    const float* __restrict__ cbias, const float* __restrict__ lng,
    const float* __restrict__ lnb, int do_elu) {
  int n = blockIdx.x;
  int t = threadIdx.x;
  int r0 = rowptr[n], r1 = rowptr[n + 1];
  int d = r1 - r0;
  __shared__ int ssrc[64];
  __shared__ float slog[64][6];
  __shared__ float m6[6], s6[6], f6[6];
  __shared__ float scratch[576];
  __shared__ float fin[96];
  __shared__ float red[2];
  int h = t / 96;
  if (t < 6) { m6[t] = -1e30f; s6[t] = 0.f; }
  float acc = 0.f;

  for (int cs = 0; cs < d; cs += 64) {
    __syncthreads();   // protects LDS reuse across chunks (and init visibility)
    int cnt = min(64, d - cs);
    if (t < cnt * 6) {
      int j = t / 6, hh = t - j * 6;
      int e = eidx[r0 + cs + j];
      slog[j][hh] = logits[(size_t)e * 6 + hh];
      if (hh == 0) ssrc[j] = src[e];
    }
    __syncthreads();
    if (t < 6) {
      float cm = -1e30f;
      for (int j = 0; j < cnt; j++) cm = fmaxf(cm, slog[j][t]);
      float mold = m6[t];
      float newm = fmaxf(mold, cm);
      float f = expf(mold - newm);   // 0 on first chunk (mold = -1e30)
      float ssum = 0.f;
      for (int j = 0; j < cnt; j++) {
        float w = expf(slog[j][t] - newm);
        slog[j][t] = w;
        ssum += w;
      }
      s6[t] = s6[t] * f + ssum;
      m6[t] = newm;
      f6[t] = f;
    }
    __syncthreads();
    float a2 = acc * f6[h];
    int j = 0;
    for (; j + 4 <= cnt; j += 4) {
      float w0 = slog[j + 0][h], w1 = slog[j + 1][h];
      float w2 = slog[j + 2][h], w3 = slog[j + 3][h];
      int s0 = ssrc[j + 0], s1 = ssrc[j + 1];
      int s2 = ssrc[j + 2], s3 = ssrc[j + 3];
      float x0 = bf2f(XLb[(size_t)s0 * 576 + t]);
      float x1 = bf2f(XLb[(size_t)s1 * 576 + t]);
      float x2 = bf2f(XLb[(size_t)s2 * 576 + t]);
      float x3 = bf2f(XLb[(size_t)s3 * 576 + t]);
      a2 += w0 * x0 + w1 * x1 + w2 * x2 + w3 * x3;
    }
    for (; j < cnt; j++)
      a2 += slog[j][h] * bf2f(XLb[(size_t)ssrc[j] * 576 + t]);
    acc = a2;
  }
  __syncthreads();
  acc *= 1.f / (s6[h] + 1e-16f);
  scratch[t] = acc;
  __syncthreads();
  if (t < 96) {
    float s = 0.f;
    for (int hh = 0; hh < 6; hh++) s += scratch[hh * 96 + t];
    s = s * (1.f / 6.f) + cbias[t];
    if (do_elu) s = (s > 0.f) ? s : expm1f(s);
    fin[t] = s;
  }
  __syncthreads();
  if (t == 0) {
    float s = 0.f, s2 = 0.f;
    for (int k = 0; k < 96; k++) { float v = fin[k]; s += v; s2 += v * v; }
    float mu = s / 96.f;
    float var = s2 / 96.f - mu * mu;
    red[0] = mu; red[1] = rsqrtf(var + 1e-5f);
  }
  __syncthreads();
  if (t < 96) {
    float y = (fin[t] - red[0]) * red[1] * lng[t] + lnb[t];
    float nv = x[(size_t)n * 96 + t] + y;
    x[(size_t)n * 96 + t] = nv;
    xb[(size_t)n * 96 + t] = f2bf(nv);
  }
}

// ---------------------------------------------------------------------------
// Predictor via MFMA (verified in R4)
// ---------------------------------------------------------------------------
__global__ __launch_bounds__(256) void pred_mfma_kernel(
    const unsigned short* __restrict__ Xb,     // [NN][96]
    const unsigned short* __restrict__ EMBb,   // [NE][96]
    const int* __restrict__ src, const int* __restrict__ dst,
    const unsigned short* __restrict__ p1wT,   // [128][288]
    const float* __restrict__ p1b, const float* __restrict__ p1g,
    const float* __restrict__ p1be,
    const unsigned short* __restrict__ p2wT,   // [64][128]
    const float* __restrict__ p2b, const float* __restrict__ p2g,
    const float* __restrict__ p2be,
    const float* __restrict__ p3w, const float* __restrict__ p3b,
    float* __restrict__ out) {
  __shared__ unsigned short h1s[4][16][136];
  int t = threadIdx.x;
  int wave = t >> 6, lane = t & 63;
  int l15 = lane & 15, quad = lane >> 4;
  int ebase = blockIdx.x * 64 + wave * 16;
  int erow = ebase + l15;
  int sN = src[erow], dN = dst[erow];

  bf16x8 A[9];
  const unsigned short* xs = &Xb[(size_t)sN * 96 + quad * 8];
  const unsigned short* xd = &Xb[(size_t)dN * 96 + quad * 8];
  const unsigned short* em = &EMBb[(size_t)erow * 96 + quad * 8];
#pragma unroll
  for (int c = 0; c < 3; c++) {
    A[c]     = *(const bf16x8*)&xs[c * 32];
    A[c + 3] = *(const bf16x8*)&xd[c * 32];
    A[c + 6] = *(const bf16x8*)&em[c * 32];
  }

  f32x4 C1[8];
#pragma unroll
  for (int nt = 0; nt < 8; nt++) {
    f32x4 acc = {0.f, 0.f, 0.f, 0.f};
    const unsigned short* bp = &p1wT[(size_t)(nt * 16 + l15) * 288 + quad * 8];
#pragma unroll
    for (int c = 0; c < 9; c++) {
      bf16x8 B = *(const bf16x8*)&bp[c * 32];
      acc = __builtin_amdgcn_mfma_f32_16x16x32_bf16(A[c], B, acc, 0, 0, 0);
    }
    float bias = p1b[nt * 16 + l15];
    acc[0] += bias; acc[1] += bias; acc[2] += bias; acc[3] += bias;
    C1[nt] = acc;
  }

  float mu1[4], rs1[4];
#pragma unroll
  for (int r = 0; r < 4; r++) {
    float s = 0.f, s2 = 0.f;
#pragma unroll
    for (int nt = 0; nt < 8; nt++) { float v = C1[nt][r]; s += v; s2 += v * v; }
    s += __shfl_xor(s, 1);  s += __shfl_xor(s, 2);
    s += __shfl_xor(s, 4);  s += __shfl_xor(s, 8);
    s2 += __shfl_xor(s2, 1); s2 += __shfl_xor(s2, 2);
    s2 += __shfl_xor(s2, 4); s2 += __shfl_xor(s2, 8);
    float mu = s * (1.f / 128.f);
    float var = s2 * (1.f / 128.f) - mu * mu;
    mu1[r] = mu;
    rs1[r] = rsqrtf(var + 1e-5f);
  }
#pragma unroll
  for (int nt = 0; nt < 8; nt++) {
    float g = p1g[nt * 16 + l15], be = p1be[nt * 16 + l15];
#pragma unroll
    for (int r = 0; r < 4; r++) {
      float v = (C1[nt][r] - mu1[r]) * rs1[r] * g + be;
      v = fmaxf(v, 0.f);
      h1s[wave][quad * 4 + r][nt * 16 + l15] = f2bf(v);
    }
  }
  __syncthreads();

  f32x4 C2[4];
#pragma unroll
  for (int nt = 0; nt < 4; nt++) {
    f32x4 acc = {0.f, 0.f, 0.f, 0.f};
    const unsigned short* bp = &p2wT[(size_t)(nt * 16 + l15) * 128 + quad * 8];
#pragma unroll
    for (int c = 0; c < 4; c++) {
      bf16x8 Af = *(const bf16x8*)&h1s[wave][l15][c * 32 + quad * 8];
      bf16x8 B = *(const bf16x8*)&bp[c * 32];
      acc = __builtin_amdgcn_mfma_f32_16x16x32_bf16(Af, B, acc, 0, 0, 0);
    }
    float bias = p2b[nt * 16 + l15];
    acc[0] += bias; acc[1] += bias; acc[2] += bias; acc[3] += bias;
    C2[nt] = acc;
  }

  float mu2[4], rs2[4];
#pragma unroll
  for (int r = 0; r < 4; r++) {
    float s = 0.f, s2 = 0.f;
#pragma unroll
    for (int nt = 0; nt < 4; nt++) { float v = C2[nt][r]; s += v; s2 += v * v; }
    s += __shfl_xor(s, 1);  s += __shfl_xor(s, 2);
    s += __shfl_xor(s, 4);  s += __shfl_xor(s, 8);
    s2 += __shfl_xor(s2, 1); s2 += __shfl_xor(s2, 2);
    s2 += __shfl_xor(s2, 4); s2 += __shfl_xor(s2, 8);
    float mu = s * (1.f / 64.f);
    float var = s2 * (1.f / 64.f) - mu * mu;
    mu2[r] = mu;
    rs2[r] = rsqrtf(var + 1e-5f);
  }

  float partial[4] = {0.f, 0.f, 0.f, 0.f};
#pragma unroll
  for (int nt = 0; nt < 4; nt++) {
    float g = p2g[nt * 16 + l15], be = p2be[nt * 16 + l15];
    float pw = p3w[nt * 16 + l15];
#pragma unroll
    for (int r = 0; r < 4; r++) {
      float v = (C2[nt][r] - mu2[r]) * rs2[r] * g + be;
      v = fmaxf(v, 0.f);
      partial[r] += v * pw;
    }
  }
#pragma unroll
  for (int r = 0; r < 4; r++) {
    float p = partial[r];
    p += __shfl_xor(p, 1);
    p += __shfl_xor(p, 2);
    p += __shfl_xor(p, 4);
    p += __shfl_xor(p, 8);
    partial[r] = p;
  }
  if (l15 == 0) {
    float b3 = p3b[0];
#pragma unroll
    for (int r = 0; r < 4; r++)
      out[ebase + quad * 4 + r] = partial[r] + b3;
  }
}

// ---------------------------------------------------------------------------
static inline size_t alignup(size_t v) { return (v + 255) & ~(size_t)255; }

extern "C" void kernel_launch(void* const* d_in, const int* in_sizes, int n_in,
                              void* d_out, int out_size, void* d_ws, size_t ws_size,
                              hipStream_t stream) {
  const float* x_in      = (const float*)d_in[0];
  const float* edge_attr = (const float*)d_in[1];
  const int*   ei        = (const int*)d_in[2];
  const int* src = ei;
  const int* dst = ei + NE;
  const float* ne_w = (const float*)d_in[3];
  const float* ne_b = (const float*)d_in[4];
  const float* ne_g = (const float*)d_in[5];
  const float* ne_be = (const float*)d_in[6];
  const float* ee_w = (const float*)d_in[7];
  const float* ee_b = (const float*)d_in[8];
  const float* ee_g = (const float*)d_in[9];
  const float* ee_be = (const float*)d_in[10];
  const float* Wl = (const float*)d_in[11];
  const float* bl = (const float*)d_in[12];
  const float* Wr = (const float*)d_in[13];
  const float* br = (const float*)d_in[14];
  const float* We = (const float*)d_in[15];
  const float* attw = (const float*)d_in[16];
  const float* cbias = (const float*)d_in[17];
  const float* lng = (const float*)d_in[18];
  const float* lnb = (const float*)d_in[19];
  const float* p1w = (const float*)d_in[20];
  const float* p1b = (const float*)d_in[21];
  const float* p1g = (const float*)d_in[22];
  const float* p1be = (const float*)d_in[23];
  const float* p2w = (const float*)d_in[24];
  const float* p2b = (const float*)d_in[25];
  const float* p2g = (const float*)d_in[26];
  const float* p2be = (const float*)d_in[27];
  const float* p3w = (const float*)d_in[28];
  const float* p3b = (const float*)d_in[29];
  float* out = (float*)d_out;

  // workspace carve (aligned)
  char* w = (char*)d_ws;
  float* X    = (float*)w; w += alignup((size_t)NN * 96 * 4);
  float* LOG  = (float*)w; w += alignup((size_t)NE * 6 * 4);
  unsigned short* EMBb = (unsigned short*)w; w += alignup((size_t)NE * 96 * 2);
  unsigned short* XLb  = (unsigned short*)w; w += alignup((size_t)NN * 576 * 2);
  unsigned short* XRb  = (unsigned short*)w; w += alignup((size_t)NN * 576 * 2);
  unsigned short* Xb   = (unsigned short*)w; w += alignup((size_t)NN * 96 * 2);
  unsigned short* WeTb = (unsigned short*)w; w += alignup((size_t)3 * 576 * 96 * 2);
  unsigned short* p1wT = (unsigned short*)w; w += alignup((size_t)128 * 288 * 2);
  unsigned short* p2wT = (unsigned short*)w; w += alignup((size_t)64 * 128 * 2);
  int* deg    = (int*)w; w += alignup((size_t)(NN + 1) * 4);
  int* rowptr = (int*)w; w += alignup((size_t)(NN + 1) * 4);
  int* cursor = (int*)w; w += alignup((size_t)NN * 4);
  int* eidx   = (int*)w; w += alignup((size_t)NE * 4);

  // encoders + weight prep
  encode_kernel<<<NN, 128, 0, stream>>>(x_in, 4, ne_w, ne_b, ne_g, ne_be, X, nullptr);
  encode_kernel<<<NE, 128, 0, stream>>>(edge_attr, 3, ee_w, ee_b, ee_g, ee_be,
                                        nullptr, EMBb);
  convW_kernel<<<(3 * 576 * 96 + 255) / 256, 256, 0, stream>>>(We, WeTb, p1w, p1wT,
                                                               p2w, p2wT);

  // CSR by dst
  hipMemsetAsync(deg, 0, (size_t)(NN + 1) * 4, stream);
  hist_kernel<<<(NE + 255) / 256, 256, 0, stream>>>(dst, deg);
  scan_kernel<<<1, 1024, 0, stream>>>(deg, rowptr, cursor);
  scatter_kernel<<<(NE + 255) / 256, 256, 0, stream>>>(dst, cursor, eidx);

  // 3 GATv2 layers
  for (int i = 0; i < 3; i++) {
    const float* Wl_i = Wl + (size_t)i * 96 * 576;
    const float* bl_i = bl + (size_t)i * 576;
    const float* Wr_i = Wr + (size_t)i * 96 * 576;
    const float* br_i = br + (size_t)i * 576;
    const unsigned short* WeT_i = WeTb + (size_t)i * 576 * 96;
    const float* aw_i = attw + (size_t)i * 576;
    const float* cb_i = cbias + (size_t)i * 96;
    const float* lg_i = lng + (size_t)i * 96;
    const float* lb_i = lnb + (size_t)i * 96;
    xlxr_kernel<<<NN / 8, 576, 0, stream>>>(X, Wl_i, bl_i, Wr_i, br_i, XLb, XRb);
    logits_mfma_kernel<<<NE / 64, 256, 0, stream>>>(EMBb, WeT_i, aw_i, XLb, XRb,
                                                    src, dst, LOG);
    aggregate_kernel<<<NN, 576, 0, stream>>>(X, Xb, XLb, LOG, rowptr, eidx, src,
                                             cb_i, lg_i, lb_i, (i < 2) ? 1 : 0);
  }

  // predictor (MFMA)
  pred_mfma_kernel<<<NE / 64, 256, 0, stream>>>(Xb, EMBb, src, dst,
                                                p1wT, p1b, p1g, p1be,
                                                p2wT, p2b, p2g, p2be,
                                                p3w, p3b, out);
}

// Round 6
// 1647.927 us; speedup vs baseline: 3.0631x; 1.1246x over previous
//
#include <hip/hip_runtime.h>
#include <math.h>

#define NN 20000
#define NE 200000
#define HIDC 96
#define NHEAD 6
#define HC 576   // NHEAD*HIDC

typedef __attribute__((ext_vector_type(8))) short bf16x8;
typedef __attribute__((ext_vector_type(4))) float f32x4;

__device__ __forceinline__ unsigned short f2bf(float x) {
  union { float f; unsigned u; } c; c.f = x;
  unsigned r = c.u + 0x7FFF + ((c.u >> 16) & 1);
  return (unsigned short)(r >> 16);
}
__device__ __forceinline__ float bf2f(unsigned short u) {
  union { unsigned u; float f; } c; c.u = ((unsigned)u) << 16;
  return c.f;
}

// ---------------------------------------------------------------------------
// Encoder: out = relu(LN(in @ W + b))   in: [rows, D], W: [D,96]
// ---------------------------------------------------------------------------
__global__ __launch_bounds__(128) void encode_kernel(
    const float* __restrict__ in, int D,
    const float* __restrict__ W, const float* __restrict__ b,
    const float* __restrict__ g, const float* __restrict__ beta,
    float* __restrict__ out, unsigned short* __restrict__ outb) {
  int row = blockIdx.x;
  int t = threadIdx.x;
  __shared__ float vin[8];
  __shared__ float part[2][2];
  __shared__ float red[2];
  if (t < D) vin[t] = in[row * D + t];
  __syncthreads();
  float v = 0.f;
  if (t < 96) {
    v = b[t];
    for (int k = 0; k < D; k++) v += vin[k] * W[k * 96 + t];
  }
  float ps = (t < 96) ? v : 0.f;
  float ps2 = (t < 96) ? v * v : 0.f;
#pragma unroll
  for (int off = 32; off > 0; off >>= 1) {
    ps += __shfl_down(ps, off);
    ps2 += __shfl_down(ps2, off);
  }
  if ((t & 63) == 0) { part[t >> 6][0] = ps; part[t >> 6][1] = ps2; }
  __syncthreads();
  if (t == 0) {
    float s = part[0][0] + part[1][0];
    float s2 = part[0][1] + part[1][1];
    float mu = s / 96.f;
    float var = s2 / 96.f - mu * mu;
    red[0] = mu; red[1] = rsqrtf(var + 1e-5f);
  }
  __syncthreads();
  if (t < 96) {
    float y = (v - red[0]) * red[1] * g[t] + beta[t];
    y = fmaxf(y, 0.f);
    if (out)  out[(size_t)row * 96 + t] = y;
    if (outb) outb[(size_t)row * 96 + t] = f2bf(y);
  }
}

// ---------------------------------------------------------------------------
// Weight prep
// ---------------------------------------------------------------------------
__global__ void convW_kernel(const float* __restrict__ We,
                             unsigned short* __restrict__ WeTb,
                             const float* __restrict__ p1w,
                             unsigned short* __restrict__ p1wT,
                             const float* __restrict__ p2w,
                             unsigned short* __restrict__ p2wT) {
  int idx = blockIdx.x * 256 + threadIdx.x;
  if (idx < 3 * 576 * 96) {
    int l = idx / (576 * 96);
    int rem = idx % (576 * 96);
    int n = rem / 96, k = rem % 96;
    WeTb[idx] = f2bf(We[(size_t)l * 96 * 576 + (size_t)k * 576 + n]);
  }
  if (idx < 128 * 288) {
    int n = idx / 288, k = idx % 288;
    p1wT[idx] = f2bf(p1w[(size_t)k * 128 + n]);
  }
  if (idx < 64 * 128) {
    int n = idx / 128, k = idx % 128;
    p2wT[idx] = f2bf(p2w[(size_t)k * 64 + n]);
  }
}

// ---------------------------------------------------------------------------
// CSR build by dst
// ---------------------------------------------------------------------------
__global__ void hist_kernel(const int* __restrict__ dst, int* __restrict__ deg) {
  int e = blockIdx.x * blockDim.x + threadIdx.x;
  if (e < NE) atomicAdd(&deg[dst[e]], 1);
}

__global__ __launch_bounds__(1024) void scan_kernel(
    const int* __restrict__ deg, int* __restrict__ rowptr, int* __restrict__ cursor) {
  __shared__ int buf[1024];
  __shared__ int carry_s;
  int t = threadIdx.x;
  if (t == 0) carry_s = 0;
  __syncthreads();
  for (int base = 0; base < NN; base += 1024) {
    int i = base + t;
    int v = (i < NN) ? deg[i] : 0;
    buf[t] = v;
    __syncthreads();
    for (int off = 1; off < 1024; off <<= 1) {
      int add = (t >= off) ? buf[t - off] : 0;
      __syncthreads();
      buf[t] += add;
      __syncthreads();
    }
    int carry = carry_s;
    int excl = carry + buf[t] - v;
    if (i < NN) { rowptr[i] = excl; cursor[i] = excl; }
    __syncthreads();
    if (t == 1023) carry_s = carry + buf[1023];
    __syncthreads();
  }
  if (t == 0) rowptr[NN] = NE;
}

// scatter: also emit permuted src/dst arrays so downstream kernels read
// contiguously in dst-sorted position order.
__global__ void scatter_kernel(const int* __restrict__ src,
                               const int* __restrict__ dst,
                               int* __restrict__ cursor, int* __restrict__ eidx,
                               int* __restrict__ srcp, int* __restrict__ dstp) {
  int e = blockIdx.x * blockDim.x + threadIdx.x;
  if (e < NE) {
    int d = dst[e];
    int p = atomicAdd(&cursor[d], 1);
    eidx[p] = e;
    srcp[p] = src[e];
    dstp[p] = d;
  }
}

// ---------------------------------------------------------------------------
// xl = x@Wl+bl, xr = x@Wr+br   (bf16 outputs only)
// ---------------------------------------------------------------------------
__global__ __launch_bounds__(576) void xlxr_kernel(
    const float* __restrict__ x,
    const float* __restrict__ Wl, const float* __restrict__ bl,
    const float* __restrict__ Wr, const float* __restrict__ br,
    unsigned short* __restrict__ xlb, unsigned short* __restrict__ xrb) {
  __shared__ float xs[8][96];
  int t = threadIdx.x;
  int n0 = blockIdx.x * 8;
  for (int idx = t; idx < 8 * 96; idx += 576)
    xs[idx / 96][idx % 96] = x[(size_t)(n0 + idx / 96) * 96 + idx % 96];
  __syncthreads();
  float aL[8], aR[8];
#pragma unroll
  for (int e = 0; e < 8; e++) { aL[e] = 0.f; aR[e] = 0.f; }
  for (int k = 0; k < 96; k += 4) {
    float wl0 = Wl[(k + 0) * 576 + t], wr0 = Wr[(k + 0) * 576 + t];
    float wl1 = Wl[(k + 1) * 576 + t], wr1 = Wr[(k + 1) * 576 + t];
    float wl2 = Wl[(k + 2) * 576 + t], wr2 = Wr[(k + 2) * 576 + t];
    float wl3 = Wl[(k + 3) * 576 + t], wr3 = Wr[(k + 3) * 576 + t];
#pragma unroll
    for (int e = 0; e < 8; e++) {
      float4 xv = *(const float4*)&xs[e][k];
      aL[e] += xv.x * wl0 + xv.y * wl1 + xv.z * wl2 + xv.w * wl3;
      aR[e] += xv.x * wr0 + xv.y * wr1 + xv.z * wr2 + xv.w * wr3;
    }
  }
  float bL = bl[t], bR = br[t];
#pragma unroll
  for (int e = 0; e < 8; e++) {
    xlb[(size_t)(n0 + e) * 576 + t] = f2bf(aL[e] + bL);
    xrb[(size_t)(n0 + e) * 576 + t] = f2bf(aR[e] + bR);
  }
}

// ---------------------------------------------------------------------------
// Logits v3: per-head phases. Phase 1: ee chunk (16 edges x 96 cols) via
// MFMA -> LDS (stride 100 = 2-way bank, free). Phase 2: 4 lanes/edge x 24
// contiguous cols; xl/xr gathered as 16B bf16x8 loads (edges in dst-sorted
// order -> xr L1 hits); ee+attw from LDS b128. logit reduced over 4 lanes.
// Output LOG in permuted (dst-sorted) position order.
// ---------------------------------------------------------------------------
__global__ __launch_bounds__(256) void logits_mfma_kernel(
    const unsigned short* __restrict__ EMBb,   // [NE][96]
    const unsigned short* __restrict__ WeTb,   // [576][96]
    const float* __restrict__ attw,            // [576]
    const unsigned short* __restrict__ XLb,    // [NN][576]
    const unsigned short* __restrict__ XRb,    // [NN][576]
    const int* __restrict__ eidx, const int* __restrict__ srcp,
    const int* __restrict__ dstp,
    float* __restrict__ logp) {               // [NE][6] permuted order
  __shared__ float ee[4][16][100];
  __shared__ float satt[576];
  __shared__ int sd[64][2];
  int t = threadIdx.x;
  int p0 = blockIdx.x * 64;
  for (int i = t; i < 576; i += 256) satt[i] = attw[i];
  if (t < 128) {
    int e = t >> 1;
    sd[e][t & 1] = (t & 1) ? dstp[p0 + e] : srcp[p0 + e];
  }
  int wave = t >> 6, lane = t & 63;
  int l15 = lane & 15, quad = lane >> 4;
  // A fragments: EMB row of edge eidx[p0 + wave*16 + l15]
  int erow = eidx[p0 + wave * 16 + l15];
  const unsigned short* arow = &EMBb[(size_t)erow * 96 + quad * 8];
  bf16x8 a0 = *(const bf16x8*)&arow[0];
  bf16x8 a1 = *(const bf16x8*)&arow[32];
  bf16x8 a2 = *(const bf16x8*)&arow[64];
  __syncthreads();

  int el2 = lane >> 2;            // edge-in-wave for phase 2
  int cq = (lane & 3) * 24;       // col-quarter within head
  int gsrc = sd[wave * 16 + el2][0];
  int gdst = sd[wave * 16 + el2][1];

  for (int h = 0; h < 6; h++) {
    // ---- phase 1: ee chunk via MFMA -> LDS ----
#pragma unroll
    for (int nt = 0; nt < 6; nt++) {
      int col = h * 96 + nt * 16 + l15;
      const unsigned short* brow = &WeTb[(size_t)col * 96 + quad * 8];
      bf16x8 b0 = *(const bf16x8*)&brow[0];
      bf16x8 b1 = *(const bf16x8*)&brow[32];
      bf16x8 b2 = *(const bf16x8*)&brow[64];
      f32x4 acc = {0.f, 0.f, 0.f, 0.f};
      acc = __builtin_amdgcn_mfma_f32_16x16x32_bf16(a0, b0, acc, 0, 0, 0);
      acc = __builtin_amdgcn_mfma_f32_16x16x32_bf16(a1, b1, acc, 0, 0, 0);
      acc = __builtin_amdgcn_mfma_f32_16x16x32_bf16(a2, b2, acc, 0, 0, 0);
#pragma unroll
      for (int r = 0; r < 4; r++)
        ee[wave][quad * 4 + r][nt * 16 + l15] = acc[r];
    }
    __syncthreads();
    // ---- phase 2: gather + leaky + attw dot ----
    const unsigned short* xlr = &XLb[(size_t)gsrc * 576 + h * 96 + cq];
    const unsigned short* xrr = &XRb[(size_t)gdst * 576 + h * 96 + cq];
    const float* eep = &ee[wave][el2][cq];
    const float* ap = &satt[h * 96 + cq];
    float partl = 0.f;
#pragma unroll
    for (int c8 = 0; c8 < 3; c8++) {
      bf16x8 xlv = *(const bf16x8*)&xlr[c8 * 8];
      bf16x8 xrv = *(const bf16x8*)&xrr[c8 * 8];
#pragma unroll
      for (int j = 0; j < 8; j++) {
        float v = eep[c8 * 8 + j] + bf2f((unsigned short)xlv[j]) +
                  bf2f((unsigned short)xrv[j]);
        v = (v > 0.f) ? v : 0.2f * v;
        partl += v * ap[c8 * 8 + j];
      }
    }
    partl += __shfl_xor(partl, 1);
    partl += __shfl_xor(partl, 2);
    if ((lane & 3) == 0)
      logp[(size_t)(p0 + wave * 16 + el2) * 6 + h] = partl;
    __syncthreads();
  }
}

// ---------------------------------------------------------------------------
// Aggregate: single-pass online softmax + weighted bf16 gather.
// LOG/srcp are in dst-sorted position order -> fully contiguous staging.
// ---------------------------------------------------------------------------
__global__ __launch_bounds__(576) void aggregate_kernel(
    float* __restrict__ x, unsigned short* __restrict__ xb,
    const unsigned short* __restrict__ XLb,
    const float* __restrict__ logp, const int* __restrict__ rowptr,
    const int* __restrict__ srcp,
    const float* __restrict__ cbias, const float* __restrict__ lng,
    const float* __restrict__ lnb, int do_elu) {
  int n = blockIdx.x;
  int t = threadIdx.x;
  int r0 = rowptr[n], r1 = rowptr[n + 1];
  int d = r1 - r0;
  __shared__ int ssrc[64];
  __shared__ float slog[64][6];
  __shared__ float m6[6], s6[6], f6[6];
  __shared__ float scratch[576];
  __shared__ float fin[96];
  __shared__ float red[2];
  int h = t / 96;
  if (t < 6) { m6[t] = -1e30f; s6[t] = 0.f; }
  float acc = 0.f;

  for (int cs = 0; cs < d; cs += 64) {
    __syncthreads();
    int cnt = min(64, d - cs);
    if (t < cnt * 6) {
      int j = t / 6, hh = t - j * 6;
      slog[j][hh] = logp[(size_t)(r0 + cs + j) * 6 + hh];
      if (hh == 0) ssrc[j] = srcp[r0 + cs + j];
    }
    __syncthreads();
    if (t < 6) {
      float cm = -1e30f;
      for (int j = 0; j < cnt; j++) cm = fmaxf(cm, slog[j][t]);
      float mold = m6[t];
      float newm = fmaxf(mold, cm);
      float f = expf(mold - newm);
      float ssum = 0.f;
      for (int j = 0; j < cnt; j++) {
        float w = expf(slog[j][t] - newm);
        slog[j][t] = w;
        ssum += w;
      }
      s6[t] = s6[t] * f + ssum;
      m6[t] = newm;
      f6[t] = f;
    }
    __syncthreads();
    float a2 = acc * f6[h];
    int j = 0;
    for (; j + 4 <= cnt; j += 4) {
      float w0 = slog[j + 0][h], w1 = slog[j + 1][h];
      float w2 = slog[j + 2][h], w3 = slog[j + 3][h];
      int s0 = ssrc[j + 0], s1 = ssrc[j + 1];
      int s2 = ssrc[j + 2], s3 = ssrc[j + 3];
      float x0 = bf2f(XLb[(size_t)s0 * 576 + t]);
      float x1 = bf2f(XLb[(size_t)s1 * 576 + t]);
      float x2 = bf2f(XLb[(size_t)s2 * 576 + t]);
      float x3 = bf2f(XLb[(size_t)s3 * 576 + t]);
      a2 += w0 * x0 + w1 * x1 + w2 * x2 + w3 * x3;
    }
    for (; j < cnt; j++)
      a2 += slog[j][h] * bf2f(XLb[(size_t)ssrc[j] * 576 + t]);
    acc = a2;
  }
  __syncthreads();
  acc *= 1.f / (s6[h] + 1e-16f);
  scratch[t] = acc;
  __syncthreads();
  if (t < 96) {
    float s = 0.f;
    for (int hh = 0; hh < 6; hh++) s += scratch[hh * 96 + t];
    s = s * (1.f / 6.f) + cbias[t];
    if (do_elu) s = (s > 0.f) ? s : expm1f(s);
    fin[t] = s;
  }
  __syncthreads();
  if (t == 0) {
    float s = 0.f, s2 = 0.f;
    for (int k = 0; k < 96; k++) { float v = fin[k]; s += v; s2 += v * v; }
    float mu = s / 96.f;
    float var = s2 / 96.f - mu * mu;
    red[0] = mu; red[1] = rsqrtf(var + 1e-5f);
  }
  __syncthreads();
  if (t < 96) {
    float y = (fin[t] - red[0]) * red[1] * lng[t] + lnb[t];
    float nv = x[(size_t)n * 96 + t] + y;
    x[(size_t)n * 96 + t] = nv;
    xb[(size_t)n * 96 + t] = f2bf(nv);
  }
}

// ---------------------------------------------------------------------------
// Predictor via MFMA (verified in R4)
// ---------------------------------------------------------------------------
__global__ __launch_bounds__(256) void pred_mfma_kernel(
    const unsigned short* __restrict__ Xb,     // [NN][96]
    const unsigned short* __restrict__ EMBb,   // [NE][96]
    const int* __restrict__ src, const int* __restrict__ dst,
    const unsigned short* __restrict__ p1wT,   // [128][288]
    const float* __restrict__ p1b, const float* __restrict__ p1g,
    const float* __restrict__ p1be,
    const unsigned short* __restrict__ p2wT,   // [64][128]
    const float* __restrict__ p2b, const float* __restrict__ p2g,
    const float* __restrict__ p2be,
    const float* __restrict__ p3w, const float* __restrict__ p3b,
    float* __restrict__ out) {
  __shared__ unsigned short h1s[4][16][136];
  int t = threadIdx.x;
  int wave = t >> 6, lane = t & 63;
  int l15 = lane & 15, quad = lane >> 4;
  int ebase = blockIdx.x * 64 + wave * 16;
  int erow = ebase + l15;
  int sN = src[erow], dN = dst[erow];

  bf16x8 A[9];
  const unsigned short* xs = &Xb[(size_t)sN * 96 + quad * 8];
  const unsigned short* xd = &Xb[(size_t)dN * 96 + quad * 8];
  const unsigned short* em = &EMBb[(size_t)erow * 96 + quad * 8];
#pragma unroll
  for (int c = 0; c < 3; c++) {
    A[c]     = *(const bf16x8*)&xs[c * 32];
    A[c + 3] = *(const bf16x8*)&xd[c * 32];
    A[c + 6] = *(const bf16x8*)&em[c * 32];
  }

  f32x4 C1[8];
#pragma unroll
  for (int nt = 0; nt < 8; nt++) {
    f32x4 acc = {0.f, 0.f, 0.f, 0.f};
    const unsigned short* bp = &p1wT[(size_t)(nt * 16 + l15) * 288 + quad * 8];
#pragma unroll
    for (int c = 0; c < 9; c++) {
      bf16x8 B = *(const bf16x8*)&bp[c * 32];
      acc = __builtin_amdgcn_mfma_f32_16x16x32_bf16(A[c], B, acc, 0, 0, 0);
    }
    float bias = p1b[nt * 16 + l15];
    acc[0] += bias; acc[1] += bias; acc[2] += bias; acc[3] += bias;
    C1[nt] = acc;
  }

  float mu1[4], rs1[4];
#pragma unroll
  for (int r = 0; r < 4; r++) {
    float s = 0.f, s2 = 0.f;
#pragma unroll
    for (int nt = 0; nt < 8; nt++) { float v = C1[nt][r]; s += v; s2 += v * v; }
    s += __shfl_xor(s, 1);  s += __shfl_xor(s, 2);
    s += __shfl_xor(s, 4);  s += __shfl_xor(s, 8);
    s2 += __shfl_xor(s2, 1); s2 += __shfl_xor(s2, 2);
    s2 += __shfl_xor(s2, 4); s2 += __shfl_xor(s2, 8);
    float mu = s * (1.f / 128.f);
    float var = s2 * (1.f / 128.f) - mu * mu;
    mu1[r] = mu;
    rs1[r] = rsqrtf(var + 1e-5f);
  }
#pragma unroll
  for (int nt = 0; nt < 8; nt++) {
    float g = p1g[nt * 16 + l15], be = p1be[nt * 16 + l15];
#pragma unroll
    for (int r = 0; r < 4; r++) {
      float v = (C1[nt][r] - mu1[r]) * rs1[r] * g + be;
      v = fmaxf(v, 0.f);
      h1s[wave][quad * 4 + r][nt * 16 + l15] = f2bf(v);
    }
  }
  __syncthreads();

  f32x4 C2[4];
#pragma unroll
  for (int nt = 0; nt < 4; nt++) {
    f32x4 acc = {0.f, 0.f, 0.f, 0.f};
    const unsigned short* bp = &p2wT[(size_t)(nt * 16 + l15) * 128 + quad * 8];
#pragma unroll
    for (int c = 0; c < 4; c++) {
      bf16x8 Af = *(const bf16x8*)&h1s[wave][l15][c * 32 + quad * 8];
      bf16x8 B = *(const bf16x8*)&bp[c * 32];
      acc = __builtin_amdgcn_mfma_f32_16x16x32_bf16(Af, B, acc, 0, 0, 0);
    }
    float bias = p2b[nt * 16 + l15];
    acc[0] += bias; acc[1] += bias; acc[2] += bias; acc[3] += bias;
    C2[nt] = acc;
  }

  float mu2[4], rs2[4];
#pragma unroll
  for (int r = 0; r < 4; r++) {
    float s = 0.f, s2 = 0.f;
#pragma unroll
    for (int nt = 0; nt < 4; nt++) { float v = C2[nt][r]; s += v; s2 += v * v; }
    s += __shfl_xor(s, 1);  s += __shfl_xor(s, 2);
    s += __shfl_xor(s, 4);  s += __shfl_xor(s, 8);
    s2 += __shfl_xor(s2, 1); s2 += __shfl_xor(s2, 2);
    s2 += __shfl_xor(s2, 4); s2 += __shfl_xor(s2, 8);
    float mu = s * (1.f / 64.f);
    float var = s2 * (1.f / 64.f) - mu * mu;
    mu2[r] = mu;
    rs2[r] = rsqrtf(var + 1e-5f);
  }

  float partial[4] = {0.f, 0.f, 0.f, 0.f};
#pragma unroll
  for (int nt = 0; nt < 4; nt++) {
    float g = p2g[nt * 16 + l15], be = p2be[nt * 16 + l15];
    float pw = p3w[nt * 16 + l15];
#pragma unroll
    for (int r = 0; r < 4; r++) {
      float v = (C2[nt][r] - mu2[r]) * rs2[r] * g + be;
      v = fmaxf(v, 0.f);
      partial[r] += v * pw;
    }
  }
#pragma unroll
  for (int r = 0; r < 4; r++) {
    float p = partial[r];
    p += __shfl_xor(p, 1);
    p += __shfl_xor(p, 2);
    p += __shfl_xor(p, 4);
    p += __shfl_xor(p, 8);
    partial[r] = p;
  }
  if (l15 == 0) {
    float b3 = p3b[0];
#pragma unroll
    for (int r = 0; r < 4; r++)
      out[ebase + quad * 4 + r] = partial[r] + b3;
  }
}

// ---------------------------------------------------------------------------
static inline size_t alignup(size_t v) { return (v + 255) & ~(size_t)255; }

extern "C" void kernel_launch(void* const* d_in, const int* in_sizes, int n_in,
                              void* d_out, int out_size, void* d_ws, size_t ws_size,
                              hipStream_t stream) {
  const float* x_in      = (const float*)d_in[0];
  const float* edge_attr = (const float*)d_in[1];
  const int*   ei        = (const int*)d_in[2];
  const int* src = ei;
  const int* dst = ei + NE;
  const float* ne_w = (const float*)d_in[3];
  const float* ne_b = (const float*)d_in[4];
  const float* ne_g = (const float*)d_in[5];
  const float* ne_be = (const float*)d_in[6];
  const float* ee_w = (const float*)d_in[7];
  const float* ee_b = (const float*)d_in[8];
  const float* ee_g = (const float*)d_in[9];
  const float* ee_be = (const float*)d_in[10];
  const float* Wl = (const float*)d_in[11];
  const float* bl = (const float*)d_in[12];
  const float* Wr = (const float*)d_in[13];
  const float* br = (const float*)d_in[14];
  const float* We = (const float*)d_in[15];
  const float* attw = (const float*)d_in[16];
  const float* cbias = (const float*)d_in[17];
  const float* lng = (const float*)d_in[18];
  const float* lnb = (const float*)d_in[19];
  const float* p1w = (const float*)d_in[20];
  const float* p1b = (const float*)d_in[21];
  const float* p1g = (const float*)d_in[22];
  const float* p1be = (const float*)d_in[23];
  const float* p2w = (const float*)d_in[24];
  const float* p2b = (const float*)d_in[25];
  const float* p2g = (const float*)d_in[26];
  const float* p2be = (const float*)d_in[27];
  const float* p3w = (const float*)d_in[28];
  const float* p3b = (const float*)d_in[29];
  float* out = (float*)d_out;

  // workspace carve (aligned)
  char* w = (char*)d_ws;
  float* X    = (float*)w; w += alignup((size_t)NN * 96 * 4);
  float* LOG  = (float*)w; w += alignup((size_t)NE * 6 * 4);
  unsigned short* EMBb = (unsigned short*)w; w += alignup((size_t)NE * 96 * 2);
  unsigned short* XLb  = (unsigned short*)w; w += alignup((size_t)NN * 576 * 2);
  unsigned short* XRb  = (unsigned short*)w; w += alignup((size_t)NN * 576 * 2);
  unsigned short* Xb   = (unsigned short*)w; w += alignup((size_t)NN * 96 * 2);
  unsigned short* WeTb = (unsigned short*)w; w += alignup((size_t)3 * 576 * 96 * 2);
  unsigned short* p1wT = (unsigned short*)w; w += alignup((size_t)128 * 288 * 2);
  unsigned short* p2wT = (unsigned short*)w; w += alignup((size_t)64 * 128 * 2);
  int* deg    = (int*)w; w += alignup((size_t)(NN + 1) * 4);
  int* rowptr = (int*)w; w += alignup((size_t)(NN + 1) * 4);
  int* cursor = (int*)w; w += alignup((size_t)NN * 4);
  int* eidx   = (int*)w; w += alignup((size_t)NE * 4);
  int* srcp   = (int*)w; w += alignup((size_t)NE * 4);
  int* dstp   = (int*)w; w += alignup((size_t)NE * 4);

  // encoders + weight prep
  encode_kernel<<<NN, 128, 0, stream>>>(x_in, 4, ne_w, ne_b, ne_g, ne_be, X, nullptr);
  encode_kernel<<<NE, 128, 0, stream>>>(edge_attr, 3, ee_w, ee_b, ee_g, ee_be,
                                        nullptr, EMBb);
  convW_kernel<<<(3 * 576 * 96 + 255) / 256, 256, 0, stream>>>(We, WeTb, p1w, p1wT,
                                                               p2w, p2wT);

  // CSR by dst
  hipMemsetAsync(deg, 0, (size_t)(NN + 1) * 4, stream);
  hist_kernel<<<(NE + 255) / 256, 256, 0, stream>>>(dst, deg);
  scan_kernel<<<1, 1024, 0, stream>>>(deg, rowptr, cursor);
  scatter_kernel<<<(NE + 255) / 256, 256, 0, stream>>>(src, dst, cursor, eidx,
                                                       srcp, dstp);

  // 3 GATv2 layers
  for (int i = 0; i < 3; i++) {
    const float* Wl_i = Wl + (size_t)i * 96 * 576;
    const float* bl_i = bl + (size_t)i * 576;
    const float* Wr_i = Wr + (size_t)i * 96 * 576;
    const float* br_i = br + (size_t)i * 576;
    const unsigned short* WeT_i = WeTb + (size_t)i * 576 * 96;
    const float* aw_i = attw + (size_t)i * 576;
    const float* cb_i = cbias + (size_t)i * 96;
    const float* lg_i = lng + (size_t)i * 96;
    const float* lb_i = lnb + (size_t)i * 96;
    xlxr_kernel<<<NN / 8, 576, 0, stream>>>(X, Wl_i, bl_i, Wr_i, br_i, XLb, XRb);
    logits_mfma_kernel<<<NE / 64, 256, 0, stream>>>(EMBb, WeT_i, aw_i, XLb, XRb,
                                                    eidx, srcp, dstp, LOG);
    aggregate_kernel<<<NN, 576, 0, stream>>>(X, Xb, XLb, LOG, rowptr, srcp,
                                             cb_i, lg_i, lb_i, (i < 2) ? 1 : 0);
  }

  // predictor (MFMA)
  pred_mfma_kernel<<<NE / 64, 256, 0, stream>>>(Xb, EMBb, src, dst,
                                                p1wT, p1b, p1g, p1be,
                                                p2wT, p2b, p2g, p2be,
                                                p3w, p3b, out);
}

// Round 7
// 1453.377 us; speedup vs baseline: 3.4732x; 1.1339x over previous
//
#include <hip/hip_runtime.h>
#include <math.h>

#define NN 20000
#define NE 200000
#define HIDC 96
#define NHEAD 6
#define HC 576   // NHEAD*HIDC

typedef __attribute__((ext_vector_type(8))) short bf16x8;
typedef __attribute__((ext_vector_type(4))) float f32x4;

__device__ __forceinline__ unsigned short f2bf(float x) {
  union { float f; unsigned u; } c; c.f = x;
  unsigned r = c.u + 0x7FFF + ((c.u >> 16) & 1);
  return (unsigned short)(r >> 16);
}
__device__ __forceinline__ float bf2f(unsigned short u) {
  union { unsigned u; float f; } c; c.u = ((unsigned)u) << 16;
  return c.f;
}

// ---------------------------------------------------------------------------
// Encoder: out = relu(LN(in @ W + b))   in: [rows, D], W: [D,96]
// ---------------------------------------------------------------------------
__global__ __launch_bounds__(128) void encode_kernel(
    const float* __restrict__ in, int D,
    const float* __restrict__ W, const float* __restrict__ b,
    const float* __restrict__ g, const float* __restrict__ beta,
    float* __restrict__ out, unsigned short* __restrict__ outb) {
  int row = blockIdx.x;
  int t = threadIdx.x;
  __shared__ float vin[8];
  __shared__ float part[2][2];
  __shared__ float red[2];
  if (t < D) vin[t] = in[row * D + t];
  __syncthreads();
  float v = 0.f;
  if (t < 96) {
    v = b[t];
    for (int k = 0; k < D; k++) v += vin[k] * W[k * 96 + t];
  }
  float ps = (t < 96) ? v : 0.f;
  float ps2 = (t < 96) ? v * v : 0.f;
#pragma unroll
  for (int off = 32; off > 0; off >>= 1) {
    ps += __shfl_down(ps, off);
    ps2 += __shfl_down(ps2, off);
  }
  if ((t & 63) == 0) { part[t >> 6][0] = ps; part[t >> 6][1] = ps2; }
  __syncthreads();
  if (t == 0) {
    float s = part[0][0] + part[1][0];
    float s2 = part[0][1] + part[1][1];
    float mu = s / 96.f;
    float var = s2 / 96.f - mu * mu;
    red[0] = mu; red[1] = rsqrtf(var + 1e-5f);
  }
  __syncthreads();
  if (t < 96) {
    float y = (v - red[0]) * red[1] * g[t] + beta[t];
    y = fmaxf(y, 0.f);
    if (out)  out[(size_t)row * 96 + t] = y;
    if (outb) outb[(size_t)row * 96 + t] = f2bf(y);
  }
}

// ---------------------------------------------------------------------------
// Weight prep
// ---------------------------------------------------------------------------
__global__ void convW_kernel(const float* __restrict__ We,
                             unsigned short* __restrict__ WeTb,
                             const float* __restrict__ p1w,
                             unsigned short* __restrict__ p1wT,
                             const float* __restrict__ p2w,
                             unsigned short* __restrict__ p2wT) {
  int idx = blockIdx.x * 256 + threadIdx.x;
  if (idx < 3 * 576 * 96) {
    int l = idx / (576 * 96);
    int rem = idx % (576 * 96);
    int n = rem / 96, k = rem % 96;
    WeTb[idx] = f2bf(We[(size_t)l * 96 * 576 + (size_t)k * 576 + n]);
  }
  if (idx < 128 * 288) {
    int n = idx / 288, k = idx % 288;
    p1wT[idx] = f2bf(p1w[(size_t)k * 128 + n]);
  }
  if (idx < 64 * 128) {
    int n = idx / 128, k = idx % 128;
    p2wT[idx] = f2bf(p2w[(size_t)k * 64 + n]);
  }
}

// ---------------------------------------------------------------------------
// CSR build by dst
// ---------------------------------------------------------------------------
__global__ void hist_kernel(const int* __restrict__ dst, int* __restrict__ deg) {
  int e = blockIdx.x * blockDim.x + threadIdx.x;
  if (e < NE) atomicAdd(&deg[dst[e]], 1);
}

__global__ __launch_bounds__(1024) void scan_kernel(
    const int* __restrict__ deg, int* __restrict__ rowptr, int* __restrict__ cursor) {
  __shared__ int buf[1024];
  __shared__ int carry_s;
  int t = threadIdx.x;
  if (t == 0) carry_s = 0;
  __syncthreads();
  for (int base = 0; base < NN; base += 1024) {
    int i = base + t;
    int v = (i < NN) ? deg[i] : 0;
    buf[t] = v;
    __syncthreads();
    for (int off = 1; off < 1024; off <<= 1) {
      int add = (t >= off) ? buf[t - off] : 0;
      __syncthreads();
      buf[t] += add;
      __syncthreads();
    }
    int carry = carry_s;
    int excl = carry + buf[t] - v;
    if (i < NN) { rowptr[i] = excl; cursor[i] = excl; }
    __syncthreads();
    if (t == 1023) carry_s = carry + buf[1023];
    __syncthreads();
  }
  if (t == 0) rowptr[NN] = NE;
}

__global__ void scatter_kernel(const int* __restrict__ src,
                               const int* __restrict__ dst,
                               int* __restrict__ cursor, int* __restrict__ eidx,
                               int* __restrict__ srcp, int* __restrict__ dstp) {
  int e = blockIdx.x * blockDim.x + threadIdx.x;
  if (e < NE) {
    int d = dst[e];
    int p = atomicAdd(&cursor[d], 1);
    eidx[p] = e;
    srcp[p] = src[e];
    dstp[p] = d;
  }
}

// ---------------------------------------------------------------------------
// xl = x@Wl+bl, xr = x@Wr+br   (bf16 outputs only)
// ---------------------------------------------------------------------------
__global__ __launch_bounds__(576) void xlxr_kernel(
    const float* __restrict__ x,
    const float* __restrict__ Wl, const float* __restrict__ bl,
    const float* __restrict__ Wr, const float* __restrict__ br,
    unsigned short* __restrict__ xlb, unsigned short* __restrict__ xrb) {
  __shared__ float xs[8][96];
  int t = threadIdx.x;
  int n0 = blockIdx.x * 8;
  for (int idx = t; idx < 8 * 96; idx += 576)
    xs[idx / 96][idx % 96] = x[(size_t)(n0 + idx / 96) * 96 + idx % 96];
  __syncthreads();
  float aL[8], aR[8];
#pragma unroll
  for (int e = 0; e < 8; e++) { aL[e] = 0.f; aR[e] = 0.f; }
  for (int k = 0; k < 96; k += 4) {
    float wl0 = Wl[(k + 0) * 576 + t], wr0 = Wr[(k + 0) * 576 + t];
    float wl1 = Wl[(k + 1) * 576 + t], wr1 = Wr[(k + 1) * 576 + t];
    float wl2 = Wl[(k + 2) * 576 + t], wr2 = Wr[(k + 2) * 576 + t];
    float wl3 = Wl[(k + 3) * 576 + t], wr3 = Wr[(k + 3) * 576 + t];
#pragma unroll
    for (int e = 0; e < 8; e++) {
      float4 xv = *(const float4*)&xs[e][k];
      aL[e] += xv.x * wl0 + xv.y * wl1 + xv.z * wl2 + xv.w * wl3;
      aR[e] += xv.x * wr0 + xv.y * wr1 + xv.z * wr2 + xv.w * wr3;
    }
  }
  float bL = bl[t], bR = br[t];
#pragma unroll
  for (int e = 0; e < 8; e++) {
    xlb[(size_t)(n0 + e) * 576 + t] = f2bf(aL[e] + bL);
    xrb[(size_t)(n0 + e) * 576 + t] = f2bf(aR[e] + bR);
  }
}

// ---------------------------------------------------------------------------
// Logits v4: 2 heads per phase. Phase 1: ee chunk (16 edges x 192 cols) via
// MFMA -> LDS (stride 196: scatter 2-way free, b128 reads uniform).
// Phase 2: 4 lanes/edge x 24 cols x 2 heads; 12 16B gathers in flight;
// attw via global/L1 float4. 6 barriers total. Output in dst-sorted order.
// ---------------------------------------------------------------------------
__global__ __launch_bounds__(256) void logits_mfma_kernel(
    const unsigned short* __restrict__ EMBb,   // [NE][96]
    const unsigned short* __restrict__ WeTb,   // [576][96]
    const float* __restrict__ attw,            // [576]
    const unsigned short* __restrict__ XLb,    // [NN][576]
    const unsigned short* __restrict__ XRb,    // [NN][576]
    const int* __restrict__ eidx, const int* __restrict__ srcp,
    const int* __restrict__ dstp,
    float* __restrict__ logp) {               // [NE][6] permuted order
  __shared__ __align__(16) float ee[4][16][196];
  __shared__ int sd[64][2];
  int t = threadIdx.x;
  int p0 = blockIdx.x * 64;
  if (t < 128) {
    int e = t >> 1;
    sd[e][t & 1] = (t & 1) ? dstp[p0 + e] : srcp[p0 + e];
  }
  int wave = t >> 6, lane = t & 63;
  int l15 = lane & 15, quad = lane >> 4;
  int erow = eidx[p0 + wave * 16 + l15];
  const unsigned short* arow = &EMBb[(size_t)erow * 96 + quad * 8];
  bf16x8 a0 = *(const bf16x8*)&arow[0];
  bf16x8 a1 = *(const bf16x8*)&arow[32];
  bf16x8 a2 = *(const bf16x8*)&arow[64];
  __syncthreads();

  int el2 = lane >> 2;            // edge-in-wave for phase 2
  int cq = (lane & 3) * 24;       // col-quarter within head
  int gsrc = sd[wave * 16 + el2][0];
  int gdst = sd[wave * 16 + el2][1];

  for (int hp = 0; hp < 3; hp++) {
    // ---- phase 1: ee for heads (2hp, 2hp+1) via MFMA -> LDS ----
#pragma unroll
    for (int nt = 0; nt < 12; nt++) {
      int col = hp * 192 + nt * 16 + l15;
      const unsigned short* brow = &WeTb[(size_t)col * 96 + quad * 8];
      bf16x8 b0 = *(const bf16x8*)&brow[0];
      bf16x8 b1 = *(const bf16x8*)&brow[32];
      bf16x8 b2 = *(const bf16x8*)&brow[64];
      f32x4 acc = {0.f, 0.f, 0.f, 0.f};
      acc = __builtin_amdgcn_mfma_f32_16x16x32_bf16(a0, b0, acc, 0, 0, 0);
      acc = __builtin_amdgcn_mfma_f32_16x16x32_bf16(a1, b1, acc, 0, 0, 0);
      acc = __builtin_amdgcn_mfma_f32_16x16x32_bf16(a2, b2, acc, 0, 0, 0);
#pragma unroll
      for (int r = 0; r < 4; r++)
        ee[wave][quad * 4 + r][nt * 16 + l15] = acc[r];
    }
    __syncthreads();
    // ---- phase 2: gather + leaky + attw dot for both heads ----
    float pl0 = 0.f, pl1 = 0.f;
    {
      int h0 = hp * 2, h1 = hp * 2 + 1;
      const unsigned short* xl0 = &XLb[(size_t)gsrc * 576 + h0 * 96 + cq];
      const unsigned short* xr0 = &XRb[(size_t)gdst * 576 + h0 * 96 + cq];
      const unsigned short* xl1 = &XLb[(size_t)gsrc * 576 + h1 * 96 + cq];
      const unsigned short* xr1 = &XRb[(size_t)gdst * 576 + h1 * 96 + cq];
      const f32x4* ee0 = (const f32x4*)&ee[wave][el2][cq];
      const f32x4* ee1 = (const f32x4*)&ee[wave][el2][96 + cq];
      const f32x4* ap0 = (const f32x4*)&attw[h0 * 96 + cq];
      const f32x4* ap1 = (const f32x4*)&attw[h1 * 96 + cq];
#pragma unroll
      for (int c8 = 0; c8 < 3; c8++) {
        bf16x8 xlv0 = *(const bf16x8*)&xl0[c8 * 8];
        bf16x8 xrv0 = *(const bf16x8*)&xr0[c8 * 8];
        bf16x8 xlv1 = *(const bf16x8*)&xl1[c8 * 8];
        bf16x8 xrv1 = *(const bf16x8*)&xr1[c8 * 8];
        f32x4 e00 = ee0[c8 * 2], e01 = ee0[c8 * 2 + 1];
        f32x4 e10 = ee1[c8 * 2], e11 = ee1[c8 * 2 + 1];
        f32x4 a00 = ap0[c8 * 2], a01 = ap0[c8 * 2 + 1];
        f32x4 a10 = ap1[c8 * 2], a11 = ap1[c8 * 2 + 1];
#pragma unroll
        for (int j = 0; j < 4; j++) {
          float v0 = e00[j] + bf2f((unsigned short)xlv0[j]) +
                     bf2f((unsigned short)xrv0[j]);
          v0 = (v0 > 0.f) ? v0 : 0.2f * v0;
          pl0 += v0 * a00[j];
          float w0 = e01[j] + bf2f((unsigned short)xlv0[j + 4]) +
                     bf2f((unsigned short)xrv0[j + 4]);
          w0 = (w0 > 0.f) ? w0 : 0.2f * w0;
          pl0 += w0 * a01[j];
          float v1 = e10[j] + bf2f((unsigned short)xlv1[j]) +
                     bf2f((unsigned short)xrv1[j]);
          v1 = (v1 > 0.f) ? v1 : 0.2f * v1;
          pl1 += v1 * a10[j];
          float w1 = e11[j] + bf2f((unsigned short)xlv1[j + 4]) +
                     bf2f((unsigned short)xrv1[j + 4]);
          w1 = (w1 > 0.f) ? w1 : 0.2f * w1;
          pl1 += w1 * a11[j];
        }
      }
    }
    pl0 += __shfl_xor(pl0, 1); pl0 += __shfl_xor(pl0, 2);
    pl1 += __shfl_xor(pl1, 1); pl1 += __shfl_xor(pl1, 2);
    if ((lane & 3) == 0) {
      size_t base = (size_t)(p0 + wave * 16 + el2) * 6 + hp * 2;
      logp[base] = pl0;
      logp[base + 1] = pl1;
    }
    __syncthreads();
  }
}

// ---------------------------------------------------------------------------
// Aggregate v3: wave-per-head online softmax (m,s in registers, shfl reduce),
// 8x-unrolled bf16 gather, shuffle-based LN epilogue.
// ---------------------------------------------------------------------------
__global__ __launch_bounds__(576) void aggregate_kernel(
    float* __restrict__ x, unsigned short* __restrict__ xb,
    const unsigned short* __restrict__ XLb,
    const float* __restrict__ logp, const int* __restrict__ rowptr,
    const int* __restrict__ srcp,
    const float* __restrict__ cbias, const float* __restrict__ lng,
    const float* __restrict__ lnb, int do_elu) {
  int n = blockIdx.x;
  int t = threadIdx.x;
  int r0 = rowptr[n], r1 = rowptr[n + 1];
  int d = r1 - r0;
  __shared__ int ssrc[64];
  __shared__ float slog[64][6];
  __shared__ float f6[6], s6f[6];
  __shared__ float scratch[576];
  __shared__ float fin[96];
  __shared__ float part[2][2];
  __shared__ float red[2];
  int wave = t >> 6, lane = t & 63;
  int h = t / 96;
  float m_w = -1e30f, s_w = 0.f;   // per-head online stats (waves 0-5 only)
  float acc = 0.f;

  for (int cs = 0; cs < d; cs += 64) {
    __syncthreads();
    int cnt = min(64, d - cs);
    if (wave == 6 && lane < cnt) ssrc[lane] = srcp[r0 + cs + lane];
    if (wave < 6) {
      float lg = (lane < cnt) ? logp[(size_t)(r0 + cs + lane) * 6 + wave]
                              : -1e30f;
      float cm = lg;
#pragma unroll
      for (int off = 32; off > 0; off >>= 1)
        cm = fmaxf(cm, __shfl_xor(cm, off));
      float newm = fmaxf(m_w, cm);
      float wgt = (lane < cnt) ? expf(lg - newm) : 0.f;
      if (lane < cnt) slog[lane][wave] = wgt;
      float ss = wgt;
#pragma unroll
      for (int off = 32; off > 0; off >>= 1)
        ss += __shfl_xor(ss, off);
      float f = expf(m_w - newm);
      s_w = s_w * f + ss;
      m_w = newm;
      if (lane == 0) f6[wave] = f;
    }
    __syncthreads();
    float a2 = acc * f6[h];
    int j = 0;
    for (; j + 8 <= cnt; j += 8) {
      float w0 = slog[j + 0][h], w1 = slog[j + 1][h];
      float w2 = slog[j + 2][h], w3 = slog[j + 3][h];
      float w4 = slog[j + 4][h], w5 = slog[j + 5][h];
      float w6 = slog[j + 6][h], w7 = slog[j + 7][h];
      int s0 = ssrc[j + 0], s1 = ssrc[j + 1], s2 = ssrc[j + 2], s3 = ssrc[j + 3];
      int s4 = ssrc[j + 4], s5 = ssrc[j + 5], s6 = ssrc[j + 6], s7 = ssrc[j + 7];
      float x0 = bf2f(XLb[(size_t)s0 * 576 + t]);
      float x1 = bf2f(XLb[(size_t)s1 * 576 + t]);
      float x2 = bf2f(XLb[(size_t)s2 * 576 + t]);
      float x3 = bf2f(XLb[(size_t)s3 * 576 + t]);
      float x4 = bf2f(XLb[(size_t)s4 * 576 + t]);
      float x5 = bf2f(XLb[(size_t)s5 * 576 + t]);
      float x6 = bf2f(XLb[(size_t)s6 * 576 + t]);
      float x7 = bf2f(XLb[(size_t)s7 * 576 + t]);
      a2 += w0 * x0 + w1 * x1 + w2 * x2 + w3 * x3 +
            w4 * x4 + w5 * x5 + w6 * x6 + w7 * x7;
    }
    for (; j < cnt; j++)
      a2 += slog[j][h] * bf2f(XLb[(size_t)ssrc[j] * 576 + t]);
    acc = a2;
  }
  if (wave < 6 && lane == 0) s6f[wave] = s_w;
  __syncthreads();
  acc *= 1.f / (s6f[h] + 1e-16f);
  scratch[t] = acc;
  __syncthreads();
  float fv = 0.f;
  if (t < 96) {
    float s = 0.f;
    for (int hh = 0; hh < 6; hh++) s += scratch[hh * 96 + t];
    s = s * (1.f / 6.f) + cbias[t];
    if (do_elu) s = (s > 0.f) ? s : expm1f(s);
    fv = s;
    fin[t] = s;
  }
  // LN reduction over 96 values via wave shuffles (waves 0 and 1)
  if (wave < 2) {
    float ps = (t < 96) ? fv : 0.f;
    float ps2 = (t < 96) ? fv * fv : 0.f;
#pragma unroll
    for (int off = 32; off > 0; off >>= 1) {
      ps += __shfl_xor(ps, off);
      ps2 += __shfl_xor(ps2, off);
    }
    if (lane == 0) { part[wave][0] = ps; part[wave][1] = ps2; }
  }
  __syncthreads();
  if (t == 0) {
    float s = part[0][0] + part[1][0];
    float s2 = part[0][1] + part[1][1];
    float mu = s / 96.f;
    float var = s2 / 96.f - mu * mu;
    red[0] = mu; red[1] = rsqrtf(var + 1e-5f);
  }
  __syncthreads();
  if (t < 96) {
    float y = (fin[t] - red[0]) * red[1] * lng[t] + lnb[t];
    float nv = x[(size_t)n * 96 + t] + y;
    x[(size_t)n * 96 + t] = nv;
    xb[(size_t)n * 96 + t] = f2bf(nv);
  }
}

// ---------------------------------------------------------------------------
// Predictor via MFMA (verified in R4)
// ---------------------------------------------------------------------------
__global__ __launch_bounds__(256) void pred_mfma_kernel(
    const unsigned short* __restrict__ Xb,     // [NN][96]
    const unsigned short* __restrict__ EMBb,   // [NE][96]
    const int* __restrict__ src, const int* __restrict__ dst,
    const unsigned short* __restrict__ p1wT,   // [128][288]
    const float* __restrict__ p1b, const float* __restrict__ p1g,
    const float* __restrict__ p1be,
    const unsigned short* __restrict__ p2wT,   // [64][128]
    const float* __restrict__ p2b, const float* __restrict__ p2g,
    const float* __restrict__ p2be,
    const float* __restrict__ p3w, const float* __restrict__ p3b,
    float* __restrict__ out) {
  __shared__ unsigned short h1s[4][16][136];
  int t = threadIdx.x;
  int wave = t >> 6, lane = t & 63;
  int l15 = lane & 15, quad = lane >> 4;
  int ebase = blockIdx.x * 64 + wave * 16;
  int erow = ebase + l15;
  int sN = src[erow], dN = dst[erow];

  bf16x8 A[9];
  const unsigned short* xs = &Xb[(size_t)sN * 96 + quad * 8];
  const unsigned short* xd = &Xb[(size_t)dN * 96 + quad * 8];
  const unsigned short* em = &EMBb[(size_t)erow * 96 + quad * 8];
#pragma unroll
  for (int c = 0; c < 3; c++) {
    A[c]     = *(const bf16x8*)&xs[c * 32];
    A[c + 3] = *(const bf16x8*)&xd[c * 32];
    A[c + 6] = *(const bf16x8*)&em[c * 32];
  }

  f32x4 C1[8];
#pragma unroll
  for (int nt = 0; nt < 8; nt++) {
    f32x4 acc = {0.f, 0.f, 0.f, 0.f};
    const unsigned short* bp = &p1wT[(size_t)(nt * 16 + l15) * 288 + quad * 8];
#pragma unroll
    for (int c = 0; c < 9; c++) {
      bf16x8 B = *(const bf16x8*)&bp[c * 32];
      acc = __builtin_amdgcn_mfma_f32_16x16x32_bf16(A[c], B, acc, 0, 0, 0);
    }
    float bias = p1b[nt * 16 + l15];
    acc[0] += bias; acc[1] += bias; acc[2] += bias; acc[3] += bias;
    C1[nt] = acc;
  }

  float mu1[4], rs1[4];
#pragma unroll
  for (int r = 0; r < 4; r++) {
    float s = 0.f, s2 = 0.f;
#pragma unroll
    for (int nt = 0; nt < 8; nt++) { float v = C1[nt][r]; s += v; s2 += v * v; }
    s += __shfl_xor(s, 1);  s += __shfl_xor(s, 2);
    s += __shfl_xor(s, 4);  s += __shfl_xor(s, 8);
    s2 += __shfl_xor(s2, 1); s2 += __shfl_xor(s2, 2);
    s2 += __shfl_xor(s2, 4); s2 += __shfl_xor(s2, 8);
    float mu = s * (1.f / 128.f);
    float var = s2 * (1.f / 128.f) - mu * mu;
    mu1[r] = mu;
    rs1[r] = rsqrtf(var + 1e-5f);
  }
#pragma unroll
  for (int nt = 0; nt < 8; nt++) {
    float g = p1g[nt * 16 + l15], be = p1be[nt * 16 + l15];
#pragma unroll
    for (int r = 0; r < 4; r++) {
      float v = (C1[nt][r] - mu1[r]) * rs1[r] * g + be;
      v = fmaxf(v, 0.f);
      h1s[wave][quad * 4 + r][nt * 16 + l15] = f2bf(v);
    }
  }
  __syncthreads();

  f32x4 C2[4];
#pragma unroll
  for (int nt = 0; nt < 4; nt++) {
    f32x4 acc = {0.f, 0.f, 0.f, 0.f};
    const unsigned short* bp = &p2wT[(size_t)(nt * 16 + l15) * 128 + quad * 8];
#pragma unroll
    for (int c = 0; c < 4; c++) {
      bf16x8 Af = *(const bf16x8*)&h1s[wave][l15][c * 32 + quad * 8];
      bf16x8 B = *(const bf16x8*)&bp[c * 32];
      acc = __builtin_amdgcn_mfma_f32_16x16x32_bf16(Af, B, acc, 0, 0, 0);
    }
    float bias = p2b[nt * 16 + l15];
    acc[0] += bias; acc[1] += bias; acc[2] += bias; acc[3] += bias;
    C2[nt] = acc;
  }

  float mu2[4], rs2[4];
#pragma unroll
  for (int r = 0; r < 4; r++) {
    float s = 0.f, s2 = 0.f;
#pragma unroll
    for (int nt = 0; nt < 4; nt++) { float v = C2[nt][r]; s += v; s2 += v * v; }
    s += __shfl_xor(s, 1);  s += __shfl_xor(s, 2);
    s += __shfl_xor(s, 4);  s += __shfl_xor(s, 8);
    s2 += __shfl_xor(s2, 1); s2 += __shfl_xor(s2, 2);
    s2 += __shfl_xor(s2, 4); s2 += __shfl_xor(s2, 8);
    float mu = s * (1.f / 64.f);
    float var = s2 * (1.f / 64.f) - mu * mu;
    mu2[r] = mu;
    rs2[r] = rsqrtf(var + 1e-5f);
  }

  float partial[4] = {0.f, 0.f, 0.f, 0.f};
#pragma unroll
  for (int nt = 0; nt < 4; nt++) {
    float g = p2g[nt * 16 + l15], be = p2be[nt * 16 + l15];
    float pw = p3w[nt * 16 + l15];
#pragma unroll
    for (int r = 0; r < 4; r++) {
      float v = (C2[nt][r] - mu2[r]) * rs2[r] * g + be;
      v = fmaxf(v, 0.f);
      partial[r] += v * pw;
    }
  }
#pragma unroll
  for (int r = 0; r < 4; r++) {
    float p = partial[r];
    p += __shfl_xor(p, 1);
    p += __shfl_xor(p, 2);
    p += __shfl_xor(p, 4);
    p += __shfl_xor(p, 8);
    partial[r] = p;
  }
  if (l15 == 0) {
    float b3 = p3b[0];
#pragma unroll
    for (int r = 0; r < 4; r++)
      out[ebase + quad * 4 + r] = partial[r] + b3;
  }
}

// ---------------------------------------------------------------------------
static inline size_t alignup(size_t v) { return (v + 255) & ~(size_t)255; }

extern "C" void kernel_launch(void* const* d_in, const int* in_sizes, int n_in,
                              void* d_out, int out_size, void* d_ws, size_t ws_size,
                              hipStream_t stream) {
  const float* x_in      = (const float*)d_in[0];
  const float* edge_attr = (const float*)d_in[1];
  const int*   ei        = (const int*)d_in[2];
  const int* src = ei;
  const int* dst = ei + NE;
  const float* ne_w = (const float*)d_in[3];
  const float* ne_b = (const float*)d_in[4];
  const float* ne_g = (const float*)d_in[5];
  const float* ne_be = (const float*)d_in[6];
  const float* ee_w = (const float*)d_in[7];
  const float* ee_b = (const float*)d_in[8];
  const float* ee_g = (const float*)d_in[9];
  const float* ee_be = (const float*)d_in[10];
  const float* Wl = (const float*)d_in[11];
  const float* bl = (const float*)d_in[12];
  const float* Wr = (const float*)d_in[13];
  const float* br = (const float*)d_in[14];
  const float* We = (const float*)d_in[15];
  const float* attw = (const float*)d_in[16];
  const float* cbias = (const float*)d_in[17];
  const float* lng = (const float*)d_in[18];
  const float* lnb = (const float*)d_in[19];
  const float* p1w = (const float*)d_in[20];
  const float* p1b = (const float*)d_in[21];
  const float* p1g = (const float*)d_in[22];
  const float* p1be = (const float*)d_in[23];
  const float* p2w = (const float*)d_in[24];
  const float* p2b = (const float*)d_in[25];
  const float* p2g = (const float*)d_in[26];
  const float* p2be = (const float*)d_in[27];
  const float* p3w = (const float*)d_in[28];
  const float* p3b = (const float*)d_in[29];
  float* out = (float*)d_out;

  // workspace carve (aligned)
  char* w = (char*)d_ws;
  float* X    = (float*)w; w += alignup((size_t)NN * 96 * 4);
  float* LOG  = (float*)w; w += alignup((size_t)NE * 6 * 4);
  unsigned short* EMBb = (unsigned short*)w; w += alignup((size_t)NE * 96 * 2);
  unsigned short* XLb  = (unsigned short*)w; w += alignup((size_t)NN * 576 * 2);
  unsigned short* XRb  = (unsigned short*)w; w += alignup((size_t)NN * 576 * 2);
  unsigned short* Xb   = (unsigned short*)w; w += alignup((size_t)NN * 96 * 2);
  unsigned short* WeTb = (unsigned short*)w; w += alignup((size_t)3 * 576 * 96 * 2);
  unsigned short* p1wT = (unsigned short*)w; w += alignup((size_t)128 * 288 * 2);
  unsigned short* p2wT = (unsigned short*)w; w += alignup((size_t)64 * 128 * 2);
  int* deg    = (int*)w; w += alignup((size_t)(NN + 1) * 4);
  int* rowptr = (int*)w; w += alignup((size_t)(NN + 1) * 4);
  int* cursor = (int*)w; w += alignup((size_t)NN * 4);
  int* eidx   = (int*)w; w += alignup((size_t)NE * 4);
  int* srcp   = (int*)w; w += alignup((size_t)NE * 4);
  int* dstp   = (int*)w; w += alignup((size_t)NE * 4);

  // encoders + weight prep
  encode_kernel<<<NN, 128, 0, stream>>>(x_in, 4, ne_w, ne_b, ne_g, ne_be, X, nullptr);
  encode_kernel<<<NE, 128, 0, stream>>>(edge_attr, 3, ee_w, ee_b, ee_g, ee_be,
                                        nullptr, EMBb);
  convW_kernel<<<(3 * 576 * 96 + 255) / 256, 256, 0, stream>>>(We, WeTb, p1w, p1wT,
                                                               p2w, p2wT);

  // CSR by dst
  hipMemsetAsync(deg, 0, (size_t)(NN + 1) * 4, stream);
  hist_kernel<<<(NE + 255) / 256, 256, 0, stream>>>(dst, deg);
  scan_kernel<<<1, 1024, 0, stream>>>(deg, rowptr, cursor);
  scatter_kernel<<<(NE + 255) / 256, 256, 0, stream>>>(src, dst, cursor, eidx,
                                                       srcp, dstp);

  // 3 GATv2 layers
  for (int i = 0; i < 3; i++) {
    const float* Wl_i = Wl + (size_t)i * 96 * 576;
    const float* bl_i = bl + (size_t)i * 576;
    const float* Wr_i = Wr + (size_t)i * 96 * 576;
    const float* br_i = br + (size_t)i * 576;
    const unsigned short* WeT_i = WeTb + (size_t)i * 576 * 96;
    const float* aw_i = attw + (size_t)i * 576;
    const float* cb_i = cbias + (size_t)i * 96;
    const float* lg_i = lng + (size_t)i * 96;
    const float* lb_i = lnb + (size_t)i * 96;
    xlxr_kernel<<<NN / 8, 576, 0, stream>>>(X, Wl_i, bl_i, Wr_i, br_i, XLb, XRb);
    logits_mfma_kernel<<<NE / 64, 256, 0, stream>>>(EMBb, WeT_i, aw_i, XLb, XRb,
                                                    eidx, srcp, dstp, LOG);
    aggregate_kernel<<<NN, 576, 0, stream>>>(X, Xb, XLb, LOG, rowptr, srcp,
                                             cb_i, lg_i, lb_i, (i < 2) ? 1 : 0);
  }

  // predictor (MFMA)
  pred_mfma_kernel<<<NE / 64, 256, 0, stream>>>(Xb, EMBb, src, dst,
                                                p1wT, p1b, p1g, p1be,
                                                p2wT, p2b, p2g, p2be,
                                                p3w, p3b, out);
}

// Round 8
// 1218.978 us; speedup vs baseline: 4.1410x; 1.1923x over previous
//
#include <hip/hip_runtime.h>
#include <math.h>

#define NN 20000
#define NE 200000
#define HIDC 96
#define NHEAD 6
#define HC 576   // NHEAD*HIDC

typedef __attribute__((ext_vector_type(8))) short bf16x8;
typedef __attribute__((ext_vector_type(4))) float f32x4;

__device__ __forceinline__ unsigned short f2bf(float x) {
  union { float f; unsigned u; } c; c.f = x;
  unsigned r = c.u + 0x7FFF + ((c.u >> 16) & 1);
  return (unsigned short)(r >> 16);
}
__device__ __forceinline__ float bf2f(unsigned short u) {
  union { unsigned u; float f; } c; c.u = ((unsigned)u) << 16;
  return c.f;
}

// ---------------------------------------------------------------------------
// Encoder: out = relu(LN(in @ W + b))   in: [rows, D], W: [D,96]
// ---------------------------------------------------------------------------
__global__ __launch_bounds__(128) void encode_kernel(
    const float* __restrict__ in, int D,
    const float* __restrict__ W, const float* __restrict__ b,
    const float* __restrict__ g, const float* __restrict__ beta,
    float* __restrict__ out, unsigned short* __restrict__ outb) {
  int row = blockIdx.x;
  int t = threadIdx.x;
  __shared__ float vin[8];
  __shared__ float part[2][2];
  __shared__ float red[2];
  if (t < D) vin[t] = in[row * D + t];
  __syncthreads();
  float v = 0.f;
  if (t < 96) {
    v = b[t];
    for (int k = 0; k < D; k++) v += vin[k] * W[k * 96 + t];
  }
  float ps = (t < 96) ? v : 0.f;
  float ps2 = (t < 96) ? v * v : 0.f;
#pragma unroll
  for (int off = 32; off > 0; off >>= 1) {
    ps += __shfl_down(ps, off);
    ps2 += __shfl_down(ps2, off);
  }
  if ((t & 63) == 0) { part[t >> 6][0] = ps; part[t >> 6][1] = ps2; }
  __syncthreads();
  if (t == 0) {
    float s = part[0][0] + part[1][0];
    float s2 = part[0][1] + part[1][1];
    float mu = s / 96.f;
    float var = s2 / 96.f - mu * mu;
    red[0] = mu; red[1] = rsqrtf(var + 1e-5f);
  }
  __syncthreads();
  if (t < 96) {
    float y = (v - red[0]) * red[1] * g[t] + beta[t];
    y = fmaxf(y, 0.f);
    if (out)  out[(size_t)row * 96 + t] = y;
    if (outb) outb[(size_t)row * 96 + t] = f2bf(y);
  }
}

// ---------------------------------------------------------------------------
// Weight prep: transpose+bf16 for We, Wl, Wr ([3][96][576] -> [3][576][96])
// and p1w/p2w.
// ---------------------------------------------------------------------------
__global__ void convW_kernel(const float* __restrict__ We,
                             unsigned short* __restrict__ WeTb,
                             const float* __restrict__ Wl,
                             unsigned short* __restrict__ WlTb,
                             const float* __restrict__ Wr,
                             unsigned short* __restrict__ WrTb,
                             const float* __restrict__ p1w,
                             unsigned short* __restrict__ p1wT,
                             const float* __restrict__ p2w,
                             unsigned short* __restrict__ p2wT) {
  int idx = blockIdx.x * 256 + threadIdx.x;
  if (idx < 3 * 576 * 96) {
    int l = idx / (576 * 96);
    int rem = idx % (576 * 96);
    int n = rem / 96, k = rem % 96;
    size_t sidx = (size_t)l * 96 * 576 + (size_t)k * 576 + n;
    WeTb[idx] = f2bf(We[sidx]);
    WlTb[idx] = f2bf(Wl[sidx]);
    WrTb[idx] = f2bf(Wr[sidx]);
  }
  if (idx < 128 * 288) {
    int n = idx / 288, k = idx % 288;
    p1wT[idx] = f2bf(p1w[(size_t)k * 128 + n]);
  }
  if (idx < 64 * 128) {
    int n = idx / 128, k = idx % 128;
    p2wT[idx] = f2bf(p2w[(size_t)k * 64 + n]);
  }
}

// ---------------------------------------------------------------------------
// CSR build by dst
// ---------------------------------------------------------------------------
__global__ void hist_kernel(const int* __restrict__ dst, int* __restrict__ deg) {
  int e = blockIdx.x * blockDim.x + threadIdx.x;
  if (e < NE) atomicAdd(&deg[dst[e]], 1);
}

__global__ __launch_bounds__(1024) void scan_kernel(
    const int* __restrict__ deg, int* __restrict__ rowptr, int* __restrict__ cursor) {
  __shared__ int buf[1024];
  __shared__ int carry_s;
  int t = threadIdx.x;
  if (t == 0) carry_s = 0;
  __syncthreads();
  for (int base = 0; base < NN; base += 1024) {
    int i = base + t;
    int v = (i < NN) ? deg[i] : 0;
    buf[t] = v;
    __syncthreads();
    for (int off = 1; off < 1024; off <<= 1) {
      int add = (t >= off) ? buf[t - off] : 0;
      __syncthreads();
      buf[t] += add;
      __syncthreads();
    }
    int carry = carry_s;
    int excl = carry + buf[t] - v;
    if (i < NN) { rowptr[i] = excl; cursor[i] = excl; }
    __syncthreads();
    if (t == 1023) carry_s = carry + buf[1023];
    __syncthreads();
  }
  if (t == 0) rowptr[NN] = NE;
}

__global__ void scatter_kernel(const int* __restrict__ src,
                               const int* __restrict__ dst,
                               int* __restrict__ cursor, int* __restrict__ eidx,
                               int* __restrict__ srcp, int* __restrict__ dstp) {
  int e = blockIdx.x * blockDim.x + threadIdx.x;
  if (e < NE) {
    int d = dst[e];
    int p = atomicAdd(&cursor[d], 1);
    eidx[p] = e;
    srcp[p] = src[e];
    dstp[p] = d;
  }
}

// ---------------------------------------------------------------------------
// xlxr via MFMA: out[node][wcol] = sum_k WT[wcol][k] * Xb[node][k] + bias.
// 256 thr = 4 waves x 16 nodes; A = WT rows (M=wcol tiles), B = Xb rows.
// C layout: col(l15)=node, row(quad*4+r)=wcol -> ushort4 packed stores.
// ---------------------------------------------------------------------------
__global__ __launch_bounds__(256) void xlxr_mfma_kernel(
    const unsigned short* __restrict__ Xb,    // [NN][96]
    const unsigned short* __restrict__ WlTb,  // [576][96]
    const float* __restrict__ bl,
    const unsigned short* __restrict__ WrTb,  // [576][96]
    const float* __restrict__ br,
    unsigned short* __restrict__ xlb, unsigned short* __restrict__ xrb) {
  int t = threadIdx.x;
  int wave = t >> 6, lane = t & 63;
  int l15 = lane & 15, quad = lane >> 4;
  int node = blockIdx.x * 64 + wave * 16 + l15;
  int nclamp = (node < NN) ? node : (NN - 1);
  bool valid = node < NN;
  const unsigned short* brow = &Xb[(size_t)nclamp * 96 + quad * 8];
  bf16x8 b0 = *(const bf16x8*)&brow[0];
  bf16x8 b1 = *(const bf16x8*)&brow[32];
  bf16x8 b2 = *(const bf16x8*)&brow[64];
#pragma unroll
  for (int mt = 0; mt < 36; mt++) {
    int wc = mt * 16 + l15;
    const unsigned short* aL = &WlTb[(size_t)wc * 96 + quad * 8];
    f32x4 accL = {0.f, 0.f, 0.f, 0.f};
    accL = __builtin_amdgcn_mfma_f32_16x16x32_bf16(*(const bf16x8*)&aL[0], b0, accL, 0, 0, 0);
    accL = __builtin_amdgcn_mfma_f32_16x16x32_bf16(*(const bf16x8*)&aL[32], b1, accL, 0, 0, 0);
    accL = __builtin_amdgcn_mfma_f32_16x16x32_bf16(*(const bf16x8*)&aL[64], b2, accL, 0, 0, 0);
    const unsigned short* aR = &WrTb[(size_t)wc * 96 + quad * 8];
    f32x4 accR = {0.f, 0.f, 0.f, 0.f};
    accR = __builtin_amdgcn_mfma_f32_16x16x32_bf16(*(const bf16x8*)&aR[0], b0, accR, 0, 0, 0);
    accR = __builtin_amdgcn_mfma_f32_16x16x32_bf16(*(const bf16x8*)&aR[32], b1, accR, 0, 0, 0);
    accR = __builtin_amdgcn_mfma_f32_16x16x32_bf16(*(const bf16x8*)&aR[64], b2, accR, 0, 0, 0);
    if (valid) {
      int c0 = mt * 16 + quad * 4;
      float4 bbL = *(const float4*)&bl[c0];
      float4 bbR = *(const float4*)&br[c0];
      ushort4 pL, pR;
      pL.x = f2bf(accL[0] + bbL.x); pL.y = f2bf(accL[1] + bbL.y);
      pL.z = f2bf(accL[2] + bbL.z); pL.w = f2bf(accL[3] + bbL.w);
      pR.x = f2bf(accR[0] + bbR.x); pR.y = f2bf(accR[1] + bbR.y);
      pR.z = f2bf(accR[2] + bbR.z); pR.w = f2bf(accR[3] + bbR.w);
      *(ushort4*)&xlb[(size_t)node * 576 + c0] = pL;
      *(ushort4*)&xrb[(size_t)node * 576 + c0] = pR;
    }
  }
}

// ---------------------------------------------------------------------------
// Logits v4 (verified R7): 2 heads per phase, MFMA ee -> LDS, wide gathers.
// ---------------------------------------------------------------------------
__global__ __launch_bounds__(256) void logits_mfma_kernel(
    const unsigned short* __restrict__ EMBb,   // [NE][96]
    const unsigned short* __restrict__ WeTb,   // [576][96]
    const float* __restrict__ attw,            // [576]
    const unsigned short* __restrict__ XLb,    // [NN][576]
    const unsigned short* __restrict__ XRb,    // [NN][576]
    const int* __restrict__ eidx, const int* __restrict__ srcp,
    const int* __restrict__ dstp,
    float* __restrict__ logp) {               // [NE][6] permuted order
  __shared__ __align__(16) float ee[4][16][196];
  __shared__ int sd[64][2];
  int t = threadIdx.x;
  int p0 = blockIdx.x * 64;
  if (t < 128) {
    int e = t >> 1;
    sd[e][t & 1] = (t & 1) ? dstp[p0 + e] : srcp[p0 + e];
  }
  int wave = t >> 6, lane = t & 63;
  int l15 = lane & 15, quad = lane >> 4;
  int erow = eidx[p0 + wave * 16 + l15];
  const unsigned short* arow = &EMBb[(size_t)erow * 96 + quad * 8];
  bf16x8 a0 = *(const bf16x8*)&arow[0];
  bf16x8 a1 = *(const bf16x8*)&arow[32];
  bf16x8 a2 = *(const bf16x8*)&arow[64];
  __syncthreads();

  int el2 = lane >> 2;
  int cq = (lane & 3) * 24;
  int gsrc = sd[wave * 16 + el2][0];
  int gdst = sd[wave * 16 + el2][1];

  for (int hp = 0; hp < 3; hp++) {
#pragma unroll
    for (int nt = 0; nt < 12; nt++) {
      int col = hp * 192 + nt * 16 + l15;
      const unsigned short* brow = &WeTb[(size_t)col * 96 + quad * 8];
      bf16x8 b0 = *(const bf16x8*)&brow[0];
      bf16x8 b1 = *(const bf16x8*)&brow[32];
      bf16x8 b2 = *(const bf16x8*)&brow[64];
      f32x4 acc = {0.f, 0.f, 0.f, 0.f};
      acc = __builtin_amdgcn_mfma_f32_16x16x32_bf16(a0, b0, acc, 0, 0, 0);
      acc = __builtin_amdgcn_mfma_f32_16x16x32_bf16(a1, b1, acc, 0, 0, 0);
      acc = __builtin_amdgcn_mfma_f32_16x16x32_bf16(a2, b2, acc, 0, 0, 0);
#pragma unroll
      for (int r = 0; r < 4; r++)
        ee[wave][quad * 4 + r][nt * 16 + l15] = acc[r];
    }
    __syncthreads();
    float pl0 = 0.f, pl1 = 0.f;
    {
      int h0 = hp * 2, h1 = hp * 2 + 1;
      const unsigned short* xl0 = &XLb[(size_t)gsrc * 576 + h0 * 96 + cq];
      const unsigned short* xr0 = &XRb[(size_t)gdst * 576 + h0 * 96 + cq];
      const unsigned short* xl1 = &XLb[(size_t)gsrc * 576 + h1 * 96 + cq];
      const unsigned short* xr1 = &XRb[(size_t)gdst * 576 + h1 * 96 + cq];
      const f32x4* ee0 = (const f32x4*)&ee[wave][el2][cq];
      const f32x4* ee1 = (const f32x4*)&ee[wave][el2][96 + cq];
      const f32x4* ap0 = (const f32x4*)&attw[h0 * 96 + cq];
      const f32x4* ap1 = (const f32x4*)&attw[h1 * 96 + cq];
#pragma unroll
      for (int c8 = 0; c8 < 3; c8++) {
        bf16x8 xlv0 = *(const bf16x8*)&xl0[c8 * 8];
        bf16x8 xrv0 = *(const bf16x8*)&xr0[c8 * 8];
        bf16x8 xlv1 = *(const bf16x8*)&xl1[c8 * 8];
        bf16x8 xrv1 = *(const bf16x8*)&xr1[c8 * 8];
        f32x4 e00 = ee0[c8 * 2], e01 = ee0[c8 * 2 + 1];
        f32x4 e10 = ee1[c8 * 2], e11 = ee1[c8 * 2 + 1];
        f32x4 a00 = ap0[c8 * 2], a01 = ap0[c8 * 2 + 1];
        f32x4 a10 = ap1[c8 * 2], a11 = ap1[c8 * 2 + 1];
#pragma unroll
        for (int j = 0; j < 4; j++) {
          float v0 = e00[j] + bf2f((unsigned short)xlv0[j]) +
                     bf2f((unsigned short)xrv0[j]);
          v0 = (v0 > 0.f) ? v0 : 0.2f * v0;
          pl0 += v0 * a00[j];
          float w0 = e01[j] + bf2f((unsigned short)xlv0[j + 4]) +
                     bf2f((unsigned short)xrv0[j + 4]);
          w0 = (w0 > 0.f) ? w0 : 0.2f * w0;
          pl0 += w0 * a01[j];
          float v1 = e10[j] + bf2f((unsigned short)xlv1[j]) +
                     bf2f((unsigned short)xrv1[j]);
          v1 = (v1 > 0.f) ? v1 : 0.2f * v1;
          pl1 += v1 * a10[j];
          float w1 = e11[j] + bf2f((unsigned short)xlv1[j + 4]) +
                     bf2f((unsigned short)xrv1[j + 4]);
          w1 = (w1 > 0.f) ? w1 : 0.2f * w1;
          pl1 += w1 * a11[j];
        }
      }
    }
    pl0 += __shfl_xor(pl0, 1); pl0 += __shfl_xor(pl0, 2);
    pl1 += __shfl_xor(pl1, 1); pl1 += __shfl_xor(pl1, 2);
    if ((lane & 3) == 0) {
      size_t base = (size_t)(p0 + wave * 16 + el2) * 6 + hp * 2;
      logp[base] = pl0;
      logp[base + 1] = pl1;
    }
    __syncthreads();
  }
}

// ---------------------------------------------------------------------------
// Alpha: wave-per-node segment softmax over dst-sorted logits.
// alpha[p][h] = exp(l - m_h) / (sum_h + 1e-16)
// ---------------------------------------------------------------------------
__global__ __launch_bounds__(256) void alpha_kernel(
    const float* __restrict__ logp, const int* __restrict__ rowptr,
    float* __restrict__ alpha) {
  int node = blockIdx.x * 4 + (threadIdx.x >> 6);
  int lane = threadIdx.x & 63;
  if (node >= NN) return;
  int r0 = rowptr[node], r1 = rowptr[node + 1];
  int d = r1 - r0;
  if (d == 0) return;
  if (d <= 64) {
    bool act = lane < d;
    int p = r0 + (act ? lane : (d - 1));
    float lg[6];
#pragma unroll
    for (int h = 0; h < 6; h++) lg[h] = logp[(size_t)p * 6 + h];
#pragma unroll
    for (int h = 0; h < 6; h++) {
      float m = act ? lg[h] : -1e30f;
#pragma unroll
      for (int off = 32; off > 0; off >>= 1) m = fmaxf(m, __shfl_xor(m, off));
      float w = act ? expf(lg[h] - m) : 0.f;
      float s = w;
#pragma unroll
      for (int off = 32; off > 0; off >>= 1) s += __shfl_xor(s, off);
      if (act) alpha[(size_t)p * 6 + h] = w / (s + 1e-16f);
    }
  } else {
    float m[6], s[6];
#pragma unroll
    for (int h = 0; h < 6; h++) { m[h] = -1e30f; s[h] = 0.f; }
    for (int cs = 0; cs < d; cs += 64) {
      int cnt = min(64, d - cs);
      bool act = lane < cnt;
      int p = r0 + cs + (act ? lane : (cnt - 1));
#pragma unroll
      for (int h = 0; h < 6; h++) {
        float lg = act ? logp[(size_t)p * 6 + h] : -1e30f;
        float cm = lg;
#pragma unroll
        for (int off = 32; off > 0; off >>= 1) cm = fmaxf(cm, __shfl_xor(cm, off));
        float newm = fmaxf(m[h], cm);
        float w = act ? expf(lg - newm) : 0.f;
        float ss = w;
#pragma unroll
        for (int off = 32; off > 0; off >>= 1) ss += __shfl_xor(ss, off);
        s[h] = s[h] * expf(m[h] - newm) + ss;
        m[h] = newm;
      }
    }
    float inv[6];
#pragma unroll
    for (int h = 0; h < 6; h++) inv[h] = 1.f / (s[h] + 1e-16f);
    for (int cs = 0; cs < d; cs += 64) {
      int cnt = min(64, d - cs);
      if (lane < cnt) {
        int p = r0 + cs + lane;
#pragma unroll
        for (int h = 0; h < 6; h++)
          alpha[(size_t)p * 6 + h] =
              expf(logp[(size_t)p * 6 + h] - m[h]) * inv[h];
      }
    }
  }
}

// ---------------------------------------------------------------------------
// Aggregate v4: barrier-free weighted gather (alpha precomputed), then
// head-mean + cbias + elu + LN + residual epilogue.
// ---------------------------------------------------------------------------
__global__ __launch_bounds__(576) void aggregate_kernel(
    float* __restrict__ x, unsigned short* __restrict__ xb,
    const unsigned short* __restrict__ XLb,
    const float* __restrict__ alpha, const int* __restrict__ rowptr,
    const int* __restrict__ srcp,
    const float* __restrict__ cbias, const float* __restrict__ lng,
    const float* __restrict__ lnb, int do_elu) {
  int n = blockIdx.x;
  int t = threadIdx.x;
  int r0 = rowptr[n];
  int d = rowptr[n + 1] - r0;
  __shared__ float scratch[576];
  __shared__ float fin[96];
  __shared__ float part[2][2];
  __shared__ float red[2];
  int wave = t >> 6, lane = t & 63;
  int h = t / 96;
  float acc = 0.f;
  int j = 0;
  for (; j + 4 <= d; j += 4) {
    int p = r0 + j;
    float w0 = alpha[(size_t)(p + 0) * 6 + h];
    float w1 = alpha[(size_t)(p + 1) * 6 + h];
    float w2 = alpha[(size_t)(p + 2) * 6 + h];
    float w3 = alpha[(size_t)(p + 3) * 6 + h];
    int s0 = srcp[p + 0], s1 = srcp[p + 1];
    int s2 = srcp[p + 2], s3 = srcp[p + 3];
    float x0 = bf2f(XLb[(size_t)s0 * 576 + t]);
    float x1 = bf2f(XLb[(size_t)s1 * 576 + t]);
    float x2 = bf2f(XLb[(size_t)s2 * 576 + t]);
    float x3 = bf2f(XLb[(size_t)s3 * 576 + t]);
    acc += w0 * x0 + w1 * x1 + w2 * x2 + w3 * x3;
  }
  for (; j < d; j++) {
    int p = r0 + j;
    acc += alpha[(size_t)p * 6 + h] * bf2f(XLb[(size_t)srcp[p] * 576 + t]);
  }
  scratch[t] = acc;
  __syncthreads();
  float fv = 0.f;
  if (t < 96) {
    float s = 0.f;
    for (int hh = 0; hh < 6; hh++) s += scratch[hh * 96 + t];
    s = s * (1.f / 6.f) + cbias[t];
    if (do_elu) s = (s > 0.f) ? s : expm1f(s);
    fv = s;
    fin[t] = s;
  }
  if (wave < 2) {
    float ps = (t < 96) ? fv : 0.f;
    float ps2 = (t < 96) ? fv * fv : 0.f;
#pragma unroll
    for (int off = 32; off > 0; off >>= 1) {
      ps += __shfl_xor(ps, off);
      ps2 += __shfl_xor(ps2, off);
    }
    if (lane == 0) { part[wave][0] = ps; part[wave][1] = ps2; }
  }
  __syncthreads();
  if (t == 0) {
    float s = part[0][0] + part[1][0];
    float s2 = part[0][1] + part[1][1];
    float mu = s / 96.f;
    float var = s2 / 96.f - mu * mu;
    red[0] = mu; red[1] = rsqrtf(var + 1e-5f);
  }
  __syncthreads();
  if (t < 96) {
    float y = (fin[t] - red[0]) * red[1] * lng[t] + lnb[t];
    float nv = x[(size_t)n * 96 + t] + y;
    x[(size_t)n * 96 + t] = nv;
    xb[(size_t)n * 96 + t] = f2bf(nv);
  }
}

// ---------------------------------------------------------------------------
// Predictor via MFMA (verified in R4)
// ---------------------------------------------------------------------------
__global__ __launch_bounds__(256) void pred_mfma_kernel(
    const unsigned short* __restrict__ Xb,     // [NN][96]
    const unsigned short* __restrict__ EMBb,   // [NE][96]
    const int* __restrict__ src, const int* __restrict__ dst,
    const unsigned short* __restrict__ p1wT,   // [128][288]
    const float* __restrict__ p1b, const float* __restrict__ p1g,
    const float* __restrict__ p1be,
    const unsigned short* __restrict__ p2wT,   // [64][128]
    const float* __restrict__ p2b, const float* __restrict__ p2g,
    const float* __restrict__ p2be,
    const float* __restrict__ p3w, const float* __restrict__ p3b,
    float* __restrict__ out) {
  __shared__ unsigned short h1s[4][16][136];
  int t = threadIdx.x;
  int wave = t >> 6, lane = t & 63;
  int l15 = lane & 15, quad = lane >> 4;
  int ebase = blockIdx.x * 64 + wave * 16;
  int erow = ebase + l15;
  int sN = src[erow], dN = dst[erow];

  bf16x8 A[9];
  const unsigned short* xs = &Xb[(size_t)sN * 96 + quad * 8];
  const unsigned short* xd = &Xb[(size_t)dN * 96 + quad * 8];
  const unsigned short* em = &EMBb[(size_t)erow * 96 + quad * 8];
#pragma unroll
  for (int c = 0; c < 3; c++) {
    A[c]     = *(const bf16x8*)&xs[c * 32];
    A[c + 3] = *(const bf16x8*)&xd[c * 32];
    A[c + 6] = *(const bf16x8*)&em[c * 32];
  }

  f32x4 C1[8];
#pragma unroll
  for (int nt = 0; nt < 8; nt++) {
    f32x4 acc = {0.f, 0.f, 0.f, 0.f};
    const unsigned short* bp = &p1wT[(size_t)(nt * 16 + l15) * 288 + quad * 8];
#pragma unroll
    for (int c = 0; c < 9; c++) {
      bf16x8 B = *(const bf16x8*)&bp[c * 32];
      acc = __builtin_amdgcn_mfma_f32_16x16x32_bf16(A[c], B, acc, 0, 0, 0);
    }
    float bias = p1b[nt * 16 + l15];
    acc[0] += bias; acc[1] += bias; acc[2] += bias; acc[3] += bias;
    C1[nt] = acc;
  }

  float mu1[4], rs1[4];
#pragma unroll
  for (int r = 0; r < 4; r++) {
    float s = 0.f, s2 = 0.f;
#pragma unroll
    for (int nt = 0; nt < 8; nt++) { float v = C1[nt][r]; s += v; s2 += v * v; }
    s += __shfl_xor(s, 1);  s += __shfl_xor(s, 2);
    s += __shfl_xor(s, 4);  s += __shfl_xor(s, 8);
    s2 += __shfl_xor(s2, 1); s2 += __shfl_xor(s2, 2);
    s2 += __shfl_xor(s2, 4); s2 += __shfl_xor(s2, 8);
    float mu = s * (1.f / 128.f);
    float var = s2 * (1.f / 128.f) - mu * mu;
    mu1[r] = mu;
    rs1[r] = rsqrtf(var + 1e-5f);
  }
#pragma unroll
  for (int nt = 0; nt < 8; nt++) {
    float g = p1g[nt * 16 + l15], be = p1be[nt * 16 + l15];
#pragma unroll
    for (int r = 0; r < 4; r++) {
      float v = (C1[nt][r] - mu1[r]) * rs1[r] * g + be;
      v = fmaxf(v, 0.f);
      h1s[wave][quad * 4 + r][nt * 16 + l15] = f2bf(v);
    }
  }
  __syncthreads();

  f32x4 C2[4];
#pragma unroll
  for (int nt = 0; nt < 4; nt++) {
    f32x4 acc = {0.f, 0.f, 0.f, 0.f};
    const unsigned short* bp = &p2wT[(size_t)(nt * 16 + l15) * 128 + quad * 8];
#pragma unroll
    for (int c = 0; c < 4; c++) {
      bf16x8 Af = *(const bf16x8*)&h1s[wave][l15][c * 32 + quad * 8];
      bf16x8 B = *(const bf16x8*)&bp[c * 32];
      acc = __builtin_amdgcn_mfma_f32_16x16x32_bf16(Af, B, acc, 0, 0, 0);
    }
    float bias = p2b[nt * 16 + l15];
    acc[0] += bias; acc[1] += bias; acc[2] += bias; acc[3] += bias;
    C2[nt] = acc;
  }

  float mu2[4], rs2[4];
#pragma unroll
  for (int r = 0; r < 4; r++) {
    float s = 0.f, s2 = 0.f;
#pragma unroll
    for (int nt = 0; nt < 4; nt++) { float v = C2[nt][r]; s += v; s2 += v * v; }
    s += __shfl_xor(s, 1);  s += __shfl_xor(s, 2);
    s += __shfl_xor(s, 4);  s += __shfl_xor(s, 8);
    s2 += __shfl_xor(s2, 1); s2 += __shfl_xor(s2, 2);
    s2 += __shfl_xor(s2, 4); s2 += __shfl_xor(s2, 8);
    float mu = s * (1.f / 64.f);
    float var = s2 * (1.f / 64.f) - mu * mu;
    mu2[r] = mu;
    rs2[r] = rsqrtf(var + 1e-5f);
  }

  float partial[4] = {0.f, 0.f, 0.f, 0.f};
#pragma unroll
  for (int nt = 0; nt < 4; nt++) {
    float g = p2g[nt * 16 + l15], be = p2be[nt * 16 + l15];
    float pw = p3w[nt * 16 + l15];
#pragma unroll
    for (int r = 0; r < 4; r++) {
      float v = (C2[nt][r] - mu2[r]) * rs2[r] * g + be;
      v = fmaxf(v, 0.f);
      partial[r] += v * pw;
    }
  }
#pragma unroll
  for (int r = 0; r < 4; r++) {
    float p = partial[r];
    p += __shfl_xor(p, 1);
    p += __shfl_xor(p, 2);
    p += __shfl_xor(p, 4);
    p += __shfl_xor(p, 8);
    partial[r] = p;
  }
  if (l15 == 0) {
    float b3 = p3b[0];
#pragma unroll
    for (int r = 0; r < 4; r++)
      out[ebase + quad * 4 + r] = partial[r] + b3;
  }
}

// ---------------------------------------------------------------------------
static inline size_t alignup(size_t v) { return (v + 255) & ~(size_t)255; }

extern "C" void kernel_launch(void* const* d_in, const int* in_sizes, int n_in,
                              void* d_out, int out_size, void* d_ws, size_t ws_size,
                              hipStream_t stream) {
  const float* x_in      = (const float*)d_in[0];
  const float* edge_attr = (const float*)d_in[1];
  const int*   ei        = (const int*)d_in[2];
  const int* src = ei;
  const int* dst = ei + NE;
  const float* ne_w = (const float*)d_in[3];
  const float* ne_b = (const float*)d_in[4];
  const float* ne_g = (const float*)d_in[5];
  const float* ne_be = (const float*)d_in[6];
  const float* ee_w = (const float*)d_in[7];
  const float* ee_b = (const float*)d_in[8];
  const float* ee_g = (const float*)d_in[9];
  const float* ee_be = (const float*)d_in[10];
  const float* Wl = (const float*)d_in[11];
  const float* bl = (const float*)d_in[12];
  const float* Wr = (const float*)d_in[13];
  const float* br = (const float*)d_in[14];
  const float* We = (const float*)d_in[15];
  const float* attw = (const float*)d_in[16];
  const float* cbias = (const float*)d_in[17];
  const float* lng = (const float*)d_in[18];
  const float* lnb = (const float*)d_in[19];
  const float* p1w = (const float*)d_in[20];
  const float* p1b = (const float*)d_in[21];
  const float* p1g = (const float*)d_in[22];
  const float* p1be = (const float*)d_in[23];
  const float* p2w = (const float*)d_in[24];
  const float* p2b = (const float*)d_in[25];
  const float* p2g = (const float*)d_in[26];
  const float* p2be = (const float*)d_in[27];
  const float* p3w = (const float*)d_in[28];
  const float* p3b = (const float*)d_in[29];
  float* out = (float*)d_out;

  // workspace carve (aligned)
  char* w = (char*)d_ws;
  float* X    = (float*)w; w += alignup((size_t)NN * 96 * 4);
  float* LOG  = (float*)w; w += alignup((size_t)NE * 6 * 4);
  float* ALPHA = (float*)w; w += alignup((size_t)NE * 6 * 4);
  unsigned short* EMBb = (unsigned short*)w; w += alignup((size_t)NE * 96 * 2);
  unsigned short* XLb  = (unsigned short*)w; w += alignup((size_t)NN * 576 * 2);
  unsigned short* XRb  = (unsigned short*)w; w += alignup((size_t)NN * 576 * 2);
  unsigned short* Xb   = (unsigned short*)w; w += alignup((size_t)NN * 96 * 2);
  unsigned short* WeTb = (unsigned short*)w; w += alignup((size_t)3 * 576 * 96 * 2);
  unsigned short* WlTb = (unsigned short*)w; w += alignup((size_t)3 * 576 * 96 * 2);
  unsigned short* WrTb = (unsigned short*)w; w += alignup((size_t)3 * 576 * 96 * 2);
  unsigned short* p1wT = (unsigned short*)w; w += alignup((size_t)128 * 288 * 2);
  unsigned short* p2wT = (unsigned short*)w; w += alignup((size_t)64 * 128 * 2);
  int* deg    = (int*)w; w += alignup((size_t)(NN + 1) * 4);
  int* rowptr = (int*)w; w += alignup((size_t)(NN + 1) * 4);
  int* cursor = (int*)w; w += alignup((size_t)NN * 4);
  int* eidx   = (int*)w; w += alignup((size_t)NE * 4);
  int* srcp   = (int*)w; w += alignup((size_t)NE * 4);
  int* dstp   = (int*)w; w += alignup((size_t)NE * 4);

  // encoders + weight prep
  encode_kernel<<<NN, 128, 0, stream>>>(x_in, 4, ne_w, ne_b, ne_g, ne_be, X, Xb);
  encode_kernel<<<NE, 128, 0, stream>>>(edge_attr, 3, ee_w, ee_b, ee_g, ee_be,
                                        nullptr, EMBb);
  convW_kernel<<<(3 * 576 * 96 + 255) / 256, 256, 0, stream>>>(
      We, WeTb, Wl, WlTb, Wr, WrTb, p1w, p1wT, p2w, p2wT);

  // CSR by dst
  hipMemsetAsync(deg, 0, (size_t)(NN + 1) * 4, stream);
  hist_kernel<<<(NE + 255) / 256, 256, 0, stream>>>(dst, deg);
  scan_kernel<<<1, 1024, 0, stream>>>(deg, rowptr, cursor);
  scatter_kernel<<<(NE + 255) / 256, 256, 0, stream>>>(src, dst, cursor, eidx,
                                                       srcp, dstp);

  // 3 GATv2 layers
  for (int i = 0; i < 3; i++) {
    const unsigned short* WlT_i = WlTb + (size_t)i * 576 * 96;
    const float* bl_i = bl + (size_t)i * 576;
    const unsigned short* WrT_i = WrTb + (size_t)i * 576 * 96;
    const float* br_i = br + (size_t)i * 576;
    const unsigned short* WeT_i = WeTb + (size_t)i * 576 * 96;
    const float* aw_i = attw + (size_t)i * 576;
    const float* cb_i = cbias + (size_t)i * 96;
    const float* lg_i = lng + (size_t)i * 96;
    const float* lb_i = lnb + (size_t)i * 96;
    xlxr_mfma_kernel<<<(NN + 63) / 64, 256, 0, stream>>>(Xb, WlT_i, bl_i,
                                                         WrT_i, br_i, XLb, XRb);
    logits_mfma_kernel<<<NE / 64, 256, 0, stream>>>(EMBb, WeT_i, aw_i, XLb, XRb,
                                                    eidx, srcp, dstp, LOG);
    alpha_kernel<<<(NN + 3) / 4, 256, 0, stream>>>(LOG, rowptr, ALPHA);
    aggregate_kernel<<<NN, 576, 0, stream>>>(X, Xb, XLb, ALPHA, rowptr, srcp,
                                             cb_i, lg_i, lb_i, (i < 2) ? 1 : 0);
  }

  // predictor (MFMA)
  pred_mfma_kernel<<<NE / 64, 256, 0, stream>>>(Xb, EMBb, src, dst,
                                                p1wT, p1b, p1g, p1be,
                                                p2wT, p2b, p2g, p2be,
                                                p3w, p3b, out);
}